// Round 7
// baseline (1499.613 us; speedup 1.0000x reference)
//
#include <hip/hip_runtime.h>

// H2GCN forward, bf16 activations in fused Jh[N,960]:
//   cols [0,64)=h [64,192)=c0 [192,448)=c1 [448,960)=c2.
// CSR build: hist -> scan -> bucketed 2-pass scatter (8B records, cache-resident
// destination buckets; kills the 11.8x write amplification of direct scatter).
// conv0/conv1: pull-SPMM bf16 gather (8B/lane, multi-row waves), fp32 acc.
// conv2: pull-SPMM over fp8 e4m3 copy of BN'd c1 (half gather bytes).
// Embed + Head: MFMA 16x16x32 bf16, weights pre-packed to B-fragment layout.

#define NN  50000
#define E1N 800000
#define E2N 1600000
#define LD  960
#define NT  3125         // 16-node tiles
#define NB  391          // row buckets of 128: (NN+127)/128

typedef short bf16x8 __attribute__((ext_vector_type(8)));
typedef float f32x4  __attribute__((ext_vector_type(4)));
typedef float f32x2  __attribute__((ext_vector_type(2)));

__device__ __forceinline__ float bfl(unsigned int w) { return __uint_as_float(w << 16); }
__device__ __forceinline__ float bfh(unsigned int w) { return __uint_as_float(w & 0xFFFF0000u); }
__device__ __forceinline__ float bf2f(unsigned short u) { return __uint_as_float(((unsigned int)u) << 16); }
__device__ __forceinline__ unsigned short f2bf(float f) {         // RNE
    unsigned int u = __float_as_uint(f);
    u += 0x7FFFu + ((u >> 16) & 1u);
    return (unsigned short)(u >> 16);
}
__device__ __forceinline__ unsigned int pack2(float a, float b) {
    return (unsigned int)f2bf(a) | ((unsigned int)f2bf(b) << 16);
}

// ---------------- setup kernels ----------------

__global__ __launch_bounds__(256) void zero_kernel(int* a, int na, int* b, int nb, float* c, int nc) {
    int i = blockIdx.x * 256 + threadIdx.x;
    if (i < na) a[i] = 0;
    if (i < nb) b[i] = 0;
    if (i < nc) c[i] = 0.f;
}

__global__ __launch_bounds__(256) void hist_kernel(const int* __restrict__ r1, const int* __restrict__ r2,
                                                   int* h1, int* h2) {
    int i = blockIdx.x * 256 + threadIdx.x;
    if (i < E1N) atomicAdd(&h1[r1[i]], 1);
    else if (i < E1N + E2N) atomicAdd(&h2[r2[i - E1N]], 1);
}

__global__ __launch_bounds__(1024) void scan_kernel(int* hist1, int* rp1, int* hist2, int* rp2) {
    int* hist = blockIdx.x ? hist2 : hist1;
    int* rp   = blockIdx.x ? rp2   : rp1;
    const int t = threadIdx.x;
    const int CH = 49;
    int base = t * CH;
    int lim = NN - base; if (lim > CH) lim = CH; if (lim < 0) lim = 0;
    int lsum = 0;
    for (int j = 0; j < lim; j++) lsum += hist[base + j];
    __shared__ int s[1024];
    s[t] = lsum;
    __syncthreads();
    for (int off = 1; off < 1024; off <<= 1) {
        int v = (t >= off) ? s[t - off] : 0;
        __syncthreads();
        s[t] += v;
        __syncthreads();
    }
    int run = s[t] - lsum;
    for (int j = 0; j < lim; j++) {
        int hv = hist[base + j];
        rp[base + j]   = run;
        hist[base + j] = run;            // cursor init (pass B)
        run += hv;
    }
    if (t == 0) rp[NN] = s[1023];
}

// bucket cursors = CSR base of each 128-row bucket
__global__ __launch_bounds__(256) void cbinit_kernel(const int* __restrict__ rp1, int* cb1,
                                                     const int* __restrict__ rp2, int* cb2) {
    int b = blockIdx.x * 256 + threadIdx.x;
    if (b < NB) { cb1[b] = rp1[b * 128]; cb2[b] = rp2[b * 128]; }
}

// pass A: append packed (row|col<<16, val) records into bucket regions of T
__global__ __launch_bounds__(256) void bucket_append_kernel(
        const int* __restrict__ r1, const int* __restrict__ c1, const float* __restrict__ v1,
        const int* __restrict__ r2, const int* __restrict__ c2, const float* __restrict__ v2,
        int* cb1, int* cb2, uint2* __restrict__ T) {
    int i = blockIdx.x * 256 + threadIdx.x;
    if (i < E1N) {
        int r = r1[i];
        uint2 rec; rec.x = (unsigned)r | ((unsigned)c1[i] << 16); rec.y = __float_as_uint(v1[i]);
        int pos = atomicAdd(&cb1[r >> 7], 1);
        T[pos] = rec;
    } else if (i < E1N + E2N) {
        int k = i - E1N;
        int r = r2[k];
        uint2 rec; rec.x = (unsigned)r | ((unsigned)c2[k] << 16); rec.y = __float_as_uint(v2[k]);
        int pos = atomicAdd(&cb2[r >> 7], 1);
        T[E1N + pos] = rec;
    }
}

// pass B: bucket-ordered records -> final CSR (col,val) uint2; dest span per bucket <=32KB
__global__ __launch_bounds__(256) void bucket_scatter_kernel(
        const uint2* __restrict__ T, int* cur1, uint2* __restrict__ Ed1,
        int* cur2, uint2* __restrict__ Ed2) {
    int i = blockIdx.x * 256 + threadIdx.x;
    if (i < E1N) {
        uint2 rec = T[i];
        int r = rec.x & 0xFFFFu;
        int pos = atomicAdd(&cur1[r], 1);
        Ed1[pos] = make_uint2(rec.x >> 16, rec.y);
    } else if (i < E1N + E2N) {
        uint2 rec = T[i];
        int r = rec.x & 0xFFFFu;
        int pos = atomicAdd(&cur2[r], 1);
        Ed2[pos] = make_uint2(rec.x >> 16, rec.y);
    }
}

// ---------------- weight -> bf16 B-fragment pack ----------------
__global__ __launch_bounds__(256) void packw_kernel(const float* __restrict__ W, unsigned short* __restrict__ Wb,
                                                    int NC, int kbs, int total) {
    int i = blockIdx.x * 256 + threadIdx.x;
    if (i >= total) return;
    int lane  = i & 63;
    int kb    = (i >> 6) % kbs;
    int ctile = i / (kbs * 64);
    int n  = ctile * 16 + (lane & 15);
    int k0 = kb * 32 + (lane >> 4) * 8;
    unsigned short v[8];
    #pragma unroll
    for (int j = 0; j < 8; j++) v[j] = f2bf(W[(k0 + j) * NC + n]);
    *(uint4*)(Wb + (size_t)i * 8) = *(uint4*)v;
}

// ---------------- embed via MFMA ----------------
__global__ __launch_bounds__(256) void embed_mfma_kernel(const float* __restrict__ x,
                                                         const unsigned short* __restrict__ Wb,
                                                         const float* __restrict__ bias,
                                                         unsigned short* __restrict__ Jh) {
    int wave = threadIdx.x >> 6;
    int lane = threadIdx.x & 63;
    int tile = blockIdx.x * 4 + wave;
    if (tile >= NT) return;
    int m = lane & 15;
    int q = lane >> 4;
    const float* xr = x + (size_t)(tile * 16 + m) * 256 + q * 8;
    const unsigned short* bbase = Wb + (size_t)lane * 8;
    f32x4 acc[4];
    #pragma unroll
    for (int ct = 0; ct < 4; ct++) acc[ct] = (f32x4){0.f, 0.f, 0.f, 0.f};
    #pragma unroll
    for (int kb = 0; kb < 8; kb++) {
        float4 xa = *(const float4*)(xr + kb * 32);
        float4 xb = *(const float4*)(xr + kb * 32 + 4);
        unsigned short av[8];
        av[0] = f2bf(xa.x); av[1] = f2bf(xa.y); av[2] = f2bf(xa.z); av[3] = f2bf(xa.w);
        av[4] = f2bf(xb.x); av[5] = f2bf(xb.y); av[6] = f2bf(xb.z); av[7] = f2bf(xb.w);
        bf16x8 a = *(bf16x8*)av;
        #pragma unroll
        for (int ct = 0; ct < 4; ct++) {
            bf16x8 bfr = *(const bf16x8*)(bbase + (size_t)(ct * 8 + kb) * 512);
            acc[ct] = __builtin_amdgcn_mfma_f32_16x16x32_bf16(a, bfr, acc[ct], 0, 0, 0);
        }
    }
    #pragma unroll
    for (int ct = 0; ct < 4; ct++) {
        int col = ct * 16 + m;
        float bb = bias[col];
        #pragma unroll
        for (int r = 0; r < 4; r++) {
            float v = fmaxf(acc[ct][r] + bb, 0.f);
            Jh[(size_t)(tile * 16 + q * 4 + r) * LD + col] = f2bf(v);
        }
    }
}

// ---------------- pull SPMM, bf16 source, LPR lanes per row (4 feats/lane) ----------------
template <int LPR>
__global__ __launch_bounds__(256) void spmm_bf16_kernel(
        const int* __restrict__ rp1, const uint2* __restrict__ ed1,
        const int* __restrict__ rp2, const uint2* __restrict__ ed2,
        const unsigned short* __restrict__ src,   // Jh + src col offset, SRCF wide
        unsigned short* __restrict__ dst) {       // Jh + dst col offset (graph1 base)
    constexpr int ROWS = 64 / LPR;
    constexpr int SRCF = LPR * 4;
    constexpr int GB   = NN / (ROWS * 4);
    int g    = (blockIdx.x >= GB) ? 1 : 0;
    int bx   = blockIdx.x - g * GB;
    int wave = threadIdx.x >> 6;
    int lane = threadIdx.x & 63;
    int grp  = lane / LPR;
    int sub  = lane % LPR;
    int row  = (bx * 4 + wave) * ROWS + grp;
    const int*   rp = g ? rp2 : rp1;
    const uint2* ed = g ? ed2 : ed1;
    int beg = rp[row], end = rp[row + 1];

    float acc[4] = {0.f, 0.f, 0.f, 0.f};
    const unsigned short* sbase = src + sub * 4;

    int j = beg;
    for (; j + 8 <= end; j += 8) {
        uint2 e[8];
        #pragma unroll
        for (int u = 0; u < 8; u++) e[u] = ed[j + u];
        uint2 s[8];
        #pragma unroll
        for (int u = 0; u < 8; u++) s[u] = *(const uint2*)(sbase + (size_t)e[u].x * LD);
        #pragma unroll
        for (int u = 0; u < 8; u++) {
            float v = __uint_as_float(e[u].y);
            acc[0]=fmaf(v,bfl(s[u].x),acc[0]); acc[1]=fmaf(v,bfh(s[u].x),acc[1]);
            acc[2]=fmaf(v,bfl(s[u].y),acc[2]); acc[3]=fmaf(v,bfh(s[u].y),acc[3]);
        }
    }
    for (; j < end; j++) {
        uint2 e = ed[j];
        float v = __uint_as_float(e.y);
        uint2 s = *(const uint2*)(sbase + (size_t)e.x * LD);
        acc[0]=fmaf(v,bfl(s.x),acc[0]); acc[1]=fmaf(v,bfh(s.x),acc[1]);
        acc[2]=fmaf(v,bfl(s.y),acc[2]); acc[3]=fmaf(v,bfh(s.y),acc[3]);
    }

    unsigned short* dp = dst + (size_t)row * LD + g * SRCF + sub * 4;
    uint2 o; o.x = pack2(acc[0], acc[1]); o.y = pack2(acc[2], acc[3]);
    *(uint2*)dp = o;
}

// ---------------- pull SPMM, fp8 e4m3 source (conv2): 64 lanes x 4 fp8 ----------------
__global__ __launch_bounds__(256) void spmm_fp8_kernel(
        const int* __restrict__ rp1, const uint2* __restrict__ ed1,
        const int* __restrict__ rp2, const uint2* __restrict__ ed2,
        const unsigned char* __restrict__ src8,   // C1f8[N,256] e4m3
        unsigned short* __restrict__ dst) {       // Jh + 448
    constexpr int GB = NN / 4;
    int g    = (blockIdx.x >= GB) ? 1 : 0;
    int bx   = blockIdx.x - g * GB;
    int wave = threadIdx.x >> 6;
    int lane = threadIdx.x & 63;
    int row  = bx * 4 + wave;
    const int*   rp = g ? rp2 : rp1;
    const uint2* ed = g ? ed2 : ed1;
    int beg = rp[row], end = rp[row + 1];

    float acc[4] = {0.f, 0.f, 0.f, 0.f};
    const unsigned char* sbase = src8 + lane * 4;

    int j = beg;
    for (; j + 8 <= end; j += 8) {
        uint2 e[8];
        #pragma unroll
        for (int u = 0; u < 8; u++) e[u] = ed[j + u];
        unsigned int s[8];
        #pragma unroll
        for (int u = 0; u < 8; u++) s[u] = *(const unsigned int*)(sbase + (size_t)e[u].x * 256);
        #pragma unroll
        for (int u = 0; u < 8; u++) {
            float v = __uint_as_float(e[u].y);
            f32x2 lo = __builtin_amdgcn_cvt_pk_f32_fp8(s[u], false);
            f32x2 hi = __builtin_amdgcn_cvt_pk_f32_fp8(s[u], true);
            acc[0]=fmaf(v,lo[0],acc[0]); acc[1]=fmaf(v,lo[1],acc[1]);
            acc[2]=fmaf(v,hi[0],acc[2]); acc[3]=fmaf(v,hi[1],acc[3]);
        }
    }
    for (; j < end; j++) {
        uint2 e = ed[j];
        float v = __uint_as_float(e.y);
        unsigned int s = *(const unsigned int*)(sbase + (size_t)e.x * 256);
        f32x2 lo = __builtin_amdgcn_cvt_pk_f32_fp8(s, false);
        f32x2 hi = __builtin_amdgcn_cvt_pk_f32_fp8(s, true);
        acc[0]=fmaf(v,lo[0],acc[0]); acc[1]=fmaf(v,lo[1],acc[1]);
        acc[2]=fmaf(v,hi[0],acc[2]); acc[3]=fmaf(v,hi[1],acc[3]);
    }

    unsigned short* dp = dst + (size_t)row * LD + g * 256 + lane * 4;
    uint2 o; o.x = pack2(acc[0], acc[1]); o.y = pack2(acc[2], acc[3]);
    *(uint2*)dp = o;
}

// ---------------- BN stats / finalize / apply ----------------
template <int F>
__global__ __launch_bounds__(256) void bn_stats_kernel(const unsigned short* __restrict__ c,
                                                       float* sum, float* sumsq) {
    constexpr int SL = 256 / F;
    int f  = threadIdx.x % F;
    int sl = threadIdx.x / F;
    float s = 0.f, ss = 0.f;
    for (int r = blockIdx.x * SL + sl; r < NN; r += gridDim.x * SL) {
        float v = bf2f(c[(size_t)r * LD + f]);
        s += v; ss += v * v;
    }
    __shared__ float ls[256], lss[256];
    ls[threadIdx.x] = s; lss[threadIdx.x] = ss;
    __syncthreads();
    if (sl == 0) {
        #pragma unroll
        for (int u = 1; u < SL; u++) { s += ls[f + u * F]; ss += lss[f + u * F]; }
        atomicAdd(&sum[f], s);
        atomicAdd(&sumsq[f], ss);
    }
}

__global__ void bn_finalize_kernel(const float* sum, const float* sumsq, const float* __restrict__ gamma,
                                   const float* __restrict__ beta, float* scale, float* shift, int F) {
    int f = blockIdx.x * blockDim.x + threadIdx.x;
    if (f >= F) return;
    float m   = sum[f] * (1.0f / NN);
    float var = sumsq[f] * (1.0f / NN) - m * m;
    float sc  = gamma[f] * rsqrtf(var + 1e-5f);
    scale[f] = sc;
    shift[f] = beta[f] - m * sc;
}

template <int F>
__global__ __launch_bounds__(256) void bn_apply_kernel(unsigned short* __restrict__ c,
                                                       const float* __restrict__ scale,
                                                       const float* __restrict__ shift) {
    constexpr int FV = F / 4;
    int idx  = blockIdx.x * 256 + threadIdx.x;
    int node = idx / FV;
    int fo   = (idx % FV) * 4;
    if (node >= NN) return;
    unsigned short* p = c + (size_t)node * LD + fo;
    uint2 v = *(uint2*)p;
    float a0 = bfl(v.x), a1 = bfh(v.x), a2 = bfl(v.y), a3 = bfh(v.y);
    float4 sc = *(const float4*)(scale + fo);
    float4 sh = *(const float4*)(shift + fo);
    a0 = fmaf(a0, sc.x, sh.x);
    a1 = fmaf(a1, sc.y, sh.y);
    a2 = fmaf(a2, sc.z, sh.z);
    a3 = fmaf(a3, sc.w, sh.w);
    v.x = pack2(a0, a1); v.y = pack2(a2, a3);
    *(uint2*)p = v;
}

// BN apply on c1 (F=256): bf16 back to Jh AND e4m3 copy for conv2's gather
__global__ __launch_bounds__(256) void bn_apply_fp8_kernel(unsigned short* __restrict__ c,
                                                           unsigned char* __restrict__ c8,
                                                           const float* __restrict__ scale,
                                                           const float* __restrict__ shift) {
    int idx  = blockIdx.x * 256 + threadIdx.x;
    int node = idx >> 6;
    int fo   = (idx & 63) * 4;
    if (node >= NN) return;
    unsigned short* p = c + (size_t)node * LD + fo;
    uint2 v = *(uint2*)p;
    float a0 = bfl(v.x), a1 = bfh(v.x), a2 = bfl(v.y), a3 = bfh(v.y);
    float4 sc = *(const float4*)(scale + fo);
    float4 sh = *(const float4*)(shift + fo);
    a0 = fmaf(a0, sc.x, sh.x);
    a1 = fmaf(a1, sc.y, sh.y);
    a2 = fmaf(a2, sc.z, sh.z);
    a3 = fmaf(a3, sc.w, sh.w);
    v.x = pack2(a0, a1); v.y = pack2(a2, a3);
    *(uint2*)p = v;
    int w = __builtin_amdgcn_cvt_pk_fp8_f32(a0, a1, 0, false);
    w     = __builtin_amdgcn_cvt_pk_fp8_f32(a2, a3, w, true);
    *(unsigned int*)(c8 + (size_t)node * 256 + fo) = (unsigned int)w;
}

// ---------------- head GEMM via MFMA ----------------
__global__ __launch_bounds__(256) void head_mfma_kernel(const unsigned short* __restrict__ Jh,
                                                        const unsigned short* __restrict__ Wb,
                                                        const float* __restrict__ b,
                                                        float* __restrict__ out) {
    int wave = threadIdx.x >> 6;
    int lane = threadIdx.x & 63;
    int tile = blockIdx.x * 4 + wave;
    if (tile >= NT) return;
    int m = lane & 15;
    int q = lane >> 4;
    const unsigned short* arow  = Jh + (size_t)(tile * 16 + m) * LD + q * 8;
    const unsigned short* bbase = Wb + (size_t)lane * 8;
    f32x4 acc0 = {0.f, 0.f, 0.f, 0.f};
    f32x4 acc1 = {0.f, 0.f, 0.f, 0.f};
    #pragma unroll 5
    for (int kb = 0; kb < 30; kb++) {
        bf16x8 a  = *(const bf16x8*)(arow + kb * 32);
        bf16x8 b0 = *(const bf16x8*)(bbase + (size_t)kb * 512);
        bf16x8 b1 = *(const bf16x8*)(bbase + (size_t)(30 + kb) * 512);
        acc0 = __builtin_amdgcn_mfma_f32_16x16x32_bf16(a, b0, acc0, 0, 0, 0);
        acc1 = __builtin_amdgcn_mfma_f32_16x16x32_bf16(a, b1, acc1, 0, 0, 0);
    }
    int col = m;
    float b0 = b[col], b1 = b[16 + col];
    #pragma unroll
    for (int r = 0; r < 4; r++) {
        float* op = out + (size_t)(tile * 16 + q * 4 + r) * 32 + col;
        op[0]  = acc0[r] + b0;
        op[16] = acc1[r] + b1;
    }
}

// ---------------- launch ----------------

extern "C" void kernel_launch(void* const* d_in, const int* in_sizes, int n_in,
                              void* d_out, int out_size, void* d_ws, size_t ws_size,
                              hipStream_t stream) {
    const float* x      = (const float*)d_in[0];
    const int*   e1_row = (const int*)d_in[1];
    const int*   e1_col = (const int*)d_in[2];
    const float* e1_val = (const float*)d_in[3];
    const int*   e2_row = (const int*)d_in[4];
    const int*   e2_col = (const int*)d_in[5];
    const float* e2_val = (const float*)d_in[6];
    const float* W_emb  = (const float*)d_in[7];
    const float* b_emb  = (const float*)d_in[8];
    const float* bn0_g  = (const float*)d_in[9];
    const float* bn0_b  = (const float*)d_in[10];
    const float* bn1_g  = (const float*)d_in[11];
    const float* bn1_b  = (const float*)d_in[12];
    const float* W_head = (const float*)d_in[13];
    const float* b_head = (const float*)d_in[14];
    float* out = (float*)d_out;

    char* ws = (char*)d_ws;
    auto alloc = [&](size_t bytes) -> char* {
        char* p = ws;
        ws += (bytes + 255) & ~(size_t)255;
        return p;
    };
    int*   rp1   = (int*)alloc((NN + 1) * 4);
    int*   cur1  = (int*)alloc(NN * 4);
    int*   rp2   = (int*)alloc((NN + 1) * 4);
    int*   cur2  = (int*)alloc(NN * 4);
    int*   cb1   = (int*)alloc(NB * 4);
    int*   cb2   = (int*)alloc(NB * 4);
    uint2* Ed1   = (uint2*)alloc((size_t)E1N * 8);
    uint2* Ed2   = (uint2*)alloc((size_t)E2N * 8);
    float* stats = (float*)alloc(1536 * 4);
    unsigned short* Wbh  = (unsigned short*)alloc(3840 * 8 * 2);
    unsigned short* Wbe  = (unsigned short*)alloc(2048 * 8 * 2);
    unsigned char*  C1f8 = (unsigned char*)alloc((size_t)NN * 256);
    unsigned short* Jh   = (unsigned short*)alloc((size_t)NN * LD * 2);
    uint2* T = (uint2*)Jh;     // temp records alias Jh (dead before embed writes Jh)

    float* sum0   = stats;        float* sq0    = stats + 128;
    float* sum1   = stats + 256;  float* sq1    = stats + 512;
    float* scale0 = stats + 768;  float* shift0 = stats + 896;
    float* scale1 = stats + 1024; float* shift1 = stats + 1280;

    const int EB = (E1N + E2N + 255) / 256;

    // CSR build (bucketed 2-pass) + weight packs
    zero_kernel<<<(NN + 255) / 256, 256, 0, stream>>>(cur1, NN, cur2, NN, stats, 768);
    hist_kernel<<<EB, 256, 0, stream>>>(e1_row, e2_row, cur1, cur2);
    scan_kernel<<<2, 1024, 0, stream>>>(cur1, rp1, cur2, rp2);
    cbinit_kernel<<<2, 256, 0, stream>>>(rp1, cb1, rp2, cb2);
    bucket_append_kernel<<<EB, 256, 0, stream>>>(e1_row, e1_col, e1_val, e2_row, e2_col, e2_val,
                                                 cb1, cb2, T);
    bucket_scatter_kernel<<<EB, 256, 0, stream>>>(T, cur1, Ed1, cur2, Ed2);
    packw_kernel<<<15, 256, 0, stream>>>(W_head, Wbh, 32, 30, 3840);
    packw_kernel<<<8, 256, 0, stream>>>(W_emb, Wbe, 64, 8, 2048);

    // embed -> Jh[:,0:64) (MFMA)
    embed_mfma_kernel<<<(NT + 3) / 4, 256, 0, stream>>>(x, Wbe, b_emb, Jh);

    // conv0 -> Jh[:,64:192), then BN
    spmm_bf16_kernel<16><<<2 * (NN / 16), 256, 0, stream>>>(rp1, Ed1, rp2, Ed2, Jh, Jh + 64);
    bn_stats_kernel<128><<<512, 256, 0, stream>>>(Jh + 64, sum0, sq0);
    bn_finalize_kernel<<<1, 128, 0, stream>>>(sum0, sq0, bn0_g, bn0_b, scale0, shift0, 128);
    bn_apply_kernel<128><<<(NN * 32 + 255) / 256, 256, 0, stream>>>(Jh + 64, scale0, shift0);

    // conv1 -> Jh[:,192:448), then BN + fp8 copy
    spmm_bf16_kernel<32><<<2 * (NN / 8), 256, 0, stream>>>(rp1, Ed1, rp2, Ed2, Jh + 64, Jh + 192);
    bn_stats_kernel<256><<<512, 256, 0, stream>>>(Jh + 192, sum1, sq1);
    bn_finalize_kernel<<<1, 256, 0, stream>>>(sum1, sq1, bn1_g, bn1_b, scale1, shift1, 256);
    bn_apply_fp8_kernel<<<(NN * 64 + 255) / 256, 256, 0, stream>>>(Jh + 192, C1f8, scale1, shift1);

    // conv2 -> Jh[:,448:960) (fp8 src)
    spmm_fp8_kernel<<<2 * (NN / 4), 256, 0, stream>>>(rp1, Ed1, rp2, Ed2, C1f8, Jh + 448);

    // head (MFMA)
    head_mfma_kernel<<<(NT + 3) / 4, 256, 0, stream>>>(Jh, Wbh, b_head, out);
}

// Round 8
// 824.157 us; speedup vs baseline: 1.8196x; 1.8196x over previous
//
#include <hip/hip_runtime.h>

// H2GCN forward, bf16 activations in fused Jh[N,960]:
//   cols [0,64)=h [64,192)=c0 [192,448)=c1 [448,960)=c2.
// CSR build: hist -> scan -> direct scatter of PACKED 4B records (col<<16|bf16val):
//   one store per edge (r6 had two 4B stores -> 227MB HBM writes; r7's bucketing
//   hit atomic contention on 782 counters -> reverted).
// conv0/conv1: pull-SPMM bf16 gather (8B/lane, multi-row waves), fp32 acc.
// conv2: pull-SPMM over fp8 e4m3 copy of BN'd c1 (half gather bytes).
// Embed + Head: MFMA 16x16x32 bf16, weights pre-packed to B-fragment layout.

#define NN  50000
#define E1N 800000
#define E2N 1600000
#define LD  960
#define NT  3125         // 16-node tiles

typedef short bf16x8 __attribute__((ext_vector_type(8)));
typedef float f32x4  __attribute__((ext_vector_type(4)));
typedef float f32x2  __attribute__((ext_vector_type(2)));

__device__ __forceinline__ float bfl(unsigned int w) { return __uint_as_float(w << 16); }
__device__ __forceinline__ float bfh(unsigned int w) { return __uint_as_float(w & 0xFFFF0000u); }
__device__ __forceinline__ float bf2f(unsigned short u) { return __uint_as_float(((unsigned int)u) << 16); }
__device__ __forceinline__ unsigned short f2bf(float f) {         // RNE
    unsigned int u = __float_as_uint(f);
    u += 0x7FFFu + ((u >> 16) & 1u);
    return (unsigned short)(u >> 16);
}
__device__ __forceinline__ unsigned int pack2(float a, float b) {
    return (unsigned int)f2bf(a) | ((unsigned int)f2bf(b) << 16);
}

// ---------------- setup kernels ----------------

__global__ __launch_bounds__(256) void zero_kernel(int* a, int na, int* b, int nb, float* c, int nc) {
    int i = blockIdx.x * 256 + threadIdx.x;
    if (i < na) a[i] = 0;
    if (i < nb) b[i] = 0;
    if (i < nc) c[i] = 0.f;
}

__global__ __launch_bounds__(256) void hist_kernel(const int* __restrict__ r1, const int* __restrict__ r2,
                                                   int* h1, int* h2) {
    int i = blockIdx.x * 256 + threadIdx.x;
    if (i < E1N) atomicAdd(&h1[r1[i]], 1);
    else if (i < E1N + E2N) atomicAdd(&h2[r2[i - E1N]], 1);
}

__global__ __launch_bounds__(1024) void scan_kernel(int* hist1, int* rp1, int* hist2, int* rp2) {
    int* hist = blockIdx.x ? hist2 : hist1;
    int* rp   = blockIdx.x ? rp2   : rp1;
    const int t = threadIdx.x;
    const int CH = 49;
    int base = t * CH;
    int lim = NN - base; if (lim > CH) lim = CH; if (lim < 0) lim = 0;
    int lsum = 0;
    for (int j = 0; j < lim; j++) lsum += hist[base + j];
    __shared__ int s[1024];
    s[t] = lsum;
    __syncthreads();
    for (int off = 1; off < 1024; off <<= 1) {
        int v = (t >= off) ? s[t - off] : 0;
        __syncthreads();
        s[t] += v;
        __syncthreads();
    }
    int run = s[t] - lsum;
    for (int j = 0; j < lim; j++) {
        int hv = hist[base + j];
        rp[base + j]   = run;
        hist[base + j] = run;            // cursor init for scatter
        run += hv;
    }
    if (t == 0) rp[NN] = s[1023];
}

// direct scatter: one packed 4B record (col<<16 | bf16(val)) per edge
__global__ __launch_bounds__(256) void scatter_kernel(
        const int* __restrict__ r1, const int* __restrict__ c1, const float* __restrict__ v1,
        const int* __restrict__ r2, const int* __restrict__ c2, const float* __restrict__ v2,
        int* cur1, unsigned int* __restrict__ Ed1, int* cur2, unsigned int* __restrict__ Ed2) {
    int i = blockIdx.x * 256 + threadIdx.x;
    if (i < E1N) {
        int r = r1[i];
        unsigned int rec = ((unsigned)c1[i] << 16) | (unsigned)f2bf(v1[i]);
        int pos = atomicAdd(&cur1[r], 1);
        Ed1[pos] = rec;
    } else if (i < E1N + E2N) {
        int k = i - E1N;
        int r = r2[k];
        unsigned int rec = ((unsigned)c2[k] << 16) | (unsigned)f2bf(v2[k]);
        int pos = atomicAdd(&cur2[r], 1);
        Ed2[pos] = rec;
    }
}

// ---------------- weight -> bf16 B-fragment pack ----------------
__global__ __launch_bounds__(256) void packw_kernel(const float* __restrict__ W, unsigned short* __restrict__ Wb,
                                                    int NC, int kbs, int total) {
    int i = blockIdx.x * 256 + threadIdx.x;
    if (i >= total) return;
    int lane  = i & 63;
    int kb    = (i >> 6) % kbs;
    int ctile = i / (kbs * 64);
    int n  = ctile * 16 + (lane & 15);
    int k0 = kb * 32 + (lane >> 4) * 8;
    unsigned short v[8];
    #pragma unroll
    for (int j = 0; j < 8; j++) v[j] = f2bf(W[(k0 + j) * NC + n]);
    *(uint4*)(Wb + (size_t)i * 8) = *(uint4*)v;
}

// ---------------- embed via MFMA ----------------
__global__ __launch_bounds__(256) void embed_mfma_kernel(const float* __restrict__ x,
                                                         const unsigned short* __restrict__ Wb,
                                                         const float* __restrict__ bias,
                                                         unsigned short* __restrict__ Jh) {
    int wave = threadIdx.x >> 6;
    int lane = threadIdx.x & 63;
    int tile = blockIdx.x * 4 + wave;
    if (tile >= NT) return;
    int m = lane & 15;
    int q = lane >> 4;
    const float* xr = x + (size_t)(tile * 16 + m) * 256 + q * 8;
    const unsigned short* bbase = Wb + (size_t)lane * 8;
    f32x4 acc[4];
    #pragma unroll
    for (int ct = 0; ct < 4; ct++) acc[ct] = (f32x4){0.f, 0.f, 0.f, 0.f};
    #pragma unroll
    for (int kb = 0; kb < 8; kb++) {
        float4 xa = *(const float4*)(xr + kb * 32);
        float4 xb = *(const float4*)(xr + kb * 32 + 4);
        unsigned short av[8];
        av[0] = f2bf(xa.x); av[1] = f2bf(xa.y); av[2] = f2bf(xa.z); av[3] = f2bf(xa.w);
        av[4] = f2bf(xb.x); av[5] = f2bf(xb.y); av[6] = f2bf(xb.z); av[7] = f2bf(xb.w);
        bf16x8 a = *(bf16x8*)av;
        #pragma unroll
        for (int ct = 0; ct < 4; ct++) {
            bf16x8 bfr = *(const bf16x8*)(bbase + (size_t)(ct * 8 + kb) * 512);
            acc[ct] = __builtin_amdgcn_mfma_f32_16x16x32_bf16(a, bfr, acc[ct], 0, 0, 0);
        }
    }
    #pragma unroll
    for (int ct = 0; ct < 4; ct++) {
        int col = ct * 16 + m;
        float bb = bias[col];
        #pragma unroll
        for (int r = 0; r < 4; r++) {
            float v = fmaxf(acc[ct][r] + bb, 0.f);
            Jh[(size_t)(tile * 16 + q * 4 + r) * LD + col] = f2bf(v);
        }
    }
}

// ---------------- pull SPMM, bf16 source, LPR lanes per row (4 feats/lane) ----------------
template <int LPR>
__global__ __launch_bounds__(256) void spmm_bf16_kernel(
        const int* __restrict__ rp1, const unsigned int* __restrict__ ed1,
        const int* __restrict__ rp2, const unsigned int* __restrict__ ed2,
        const unsigned short* __restrict__ src,   // Jh + src col offset, SRCF wide
        unsigned short* __restrict__ dst) {       // Jh + dst col offset (graph1 base)
    constexpr int ROWS = 64 / LPR;
    constexpr int SRCF = LPR * 4;
    constexpr int GB   = NN / (ROWS * 4);
    int g    = (blockIdx.x >= GB) ? 1 : 0;
    int bx   = blockIdx.x - g * GB;
    int wave = threadIdx.x >> 6;
    int lane = threadIdx.x & 63;
    int grp  = lane / LPR;
    int sub  = lane % LPR;
    int row  = (bx * 4 + wave) * ROWS + grp;
    const int*          rp = g ? rp2 : rp1;
    const unsigned int* ed = g ? ed2 : ed1;
    int beg = rp[row], end = rp[row + 1];

    float acc[4] = {0.f, 0.f, 0.f, 0.f};
    const unsigned short* sbase = src + sub * 4;

    int j = beg;
    for (; j + 8 <= end; j += 8) {
        unsigned int e[8];
        #pragma unroll
        for (int u = 0; u < 8; u++) e[u] = ed[j + u];
        uint2 s[8];
        #pragma unroll
        for (int u = 0; u < 8; u++) s[u] = *(const uint2*)(sbase + (size_t)(e[u] >> 16) * LD);
        #pragma unroll
        for (int u = 0; u < 8; u++) {
            float v = bfl(e[u]);
            acc[0]=fmaf(v,bfl(s[u].x),acc[0]); acc[1]=fmaf(v,bfh(s[u].x),acc[1]);
            acc[2]=fmaf(v,bfl(s[u].y),acc[2]); acc[3]=fmaf(v,bfh(s[u].y),acc[3]);
        }
    }
    for (; j < end; j++) {
        unsigned int e = ed[j];
        float v = bfl(e);
        uint2 s = *(const uint2*)(sbase + (size_t)(e >> 16) * LD);
        acc[0]=fmaf(v,bfl(s.x),acc[0]); acc[1]=fmaf(v,bfh(s.x),acc[1]);
        acc[2]=fmaf(v,bfl(s.y),acc[2]); acc[3]=fmaf(v,bfh(s.y),acc[3]);
    }

    unsigned short* dp = dst + (size_t)row * LD + g * SRCF + sub * 4;
    uint2 o; o.x = pack2(acc[0], acc[1]); o.y = pack2(acc[2], acc[3]);
    *(uint2*)dp = o;
}

// ---------------- pull SPMM, fp8 e4m3 source (conv2): 64 lanes x 4 fp8 ----------------
__global__ __launch_bounds__(256) void spmm_fp8_kernel(
        const int* __restrict__ rp1, const unsigned int* __restrict__ ed1,
        const int* __restrict__ rp2, const unsigned int* __restrict__ ed2,
        const unsigned char* __restrict__ src8,   // C1f8[N,256] e4m3
        unsigned short* __restrict__ dst) {       // Jh + 448
    constexpr int GB = NN / 4;
    int g    = (blockIdx.x >= GB) ? 1 : 0;
    int bx   = blockIdx.x - g * GB;
    int wave = threadIdx.x >> 6;
    int lane = threadIdx.x & 63;
    int row  = bx * 4 + wave;
    const int*          rp = g ? rp2 : rp1;
    const unsigned int* ed = g ? ed2 : ed1;
    int beg = rp[row], end = rp[row + 1];

    float acc[4] = {0.f, 0.f, 0.f, 0.f};
    const unsigned char* sbase = src8 + lane * 4;

    int j = beg;
    for (; j + 8 <= end; j += 8) {
        unsigned int e[8];
        #pragma unroll
        for (int u = 0; u < 8; u++) e[u] = ed[j + u];
        unsigned int s[8];
        #pragma unroll
        for (int u = 0; u < 8; u++) s[u] = *(const unsigned int*)(sbase + (size_t)(e[u] >> 16) * 256);
        #pragma unroll
        for (int u = 0; u < 8; u++) {
            float v = bfl(e[u]);
            f32x2 lo = __builtin_amdgcn_cvt_pk_f32_fp8(s[u], false);
            f32x2 hi = __builtin_amdgcn_cvt_pk_f32_fp8(s[u], true);
            acc[0]=fmaf(v,lo[0],acc[0]); acc[1]=fmaf(v,lo[1],acc[1]);
            acc[2]=fmaf(v,hi[0],acc[2]); acc[3]=fmaf(v,hi[1],acc[3]);
        }
    }
    for (; j < end; j++) {
        unsigned int e = ed[j];
        float v = bfl(e);
        unsigned int s = *(const unsigned int*)(sbase + (size_t)(e >> 16) * 256);
        f32x2 lo = __builtin_amdgcn_cvt_pk_f32_fp8(s, false);
        f32x2 hi = __builtin_amdgcn_cvt_pk_f32_fp8(s, true);
        acc[0]=fmaf(v,lo[0],acc[0]); acc[1]=fmaf(v,lo[1],acc[1]);
        acc[2]=fmaf(v,hi[0],acc[2]); acc[3]=fmaf(v,hi[1],acc[3]);
    }

    unsigned short* dp = dst + (size_t)row * LD + g * 256 + lane * 4;
    uint2 o; o.x = pack2(acc[0], acc[1]); o.y = pack2(acc[2], acc[3]);
    *(uint2*)dp = o;
}

// ---------------- BN stats / finalize / apply ----------------
template <int F>
__global__ __launch_bounds__(256) void bn_stats_kernel(const unsigned short* __restrict__ c,
                                                       float* sum, float* sumsq) {
    constexpr int SL = 256 / F;
    int f  = threadIdx.x % F;
    int sl = threadIdx.x / F;
    float s = 0.f, ss = 0.f;
    for (int r = blockIdx.x * SL + sl; r < NN; r += gridDim.x * SL) {
        float v = bf2f(c[(size_t)r * LD + f]);
        s += v; ss += v * v;
    }
    __shared__ float ls[256], lss[256];
    ls[threadIdx.x] = s; lss[threadIdx.x] = ss;
    __syncthreads();
    if (sl == 0) {
        #pragma unroll
        for (int u = 1; u < SL; u++) { s += ls[f + u * F]; ss += lss[f + u * F]; }
        atomicAdd(&sum[f], s);
        atomicAdd(&sumsq[f], ss);
    }
}

__global__ void bn_finalize_kernel(const float* sum, const float* sumsq, const float* __restrict__ gamma,
                                   const float* __restrict__ beta, float* scale, float* shift, int F) {
    int f = blockIdx.x * blockDim.x + threadIdx.x;
    if (f >= F) return;
    float m   = sum[f] * (1.0f / NN);
    float var = sumsq[f] * (1.0f / NN) - m * m;
    float sc  = gamma[f] * rsqrtf(var + 1e-5f);
    scale[f] = sc;
    shift[f] = beta[f] - m * sc;
}

template <int F>
__global__ __launch_bounds__(256) void bn_apply_kernel(unsigned short* __restrict__ c,
                                                       const float* __restrict__ scale,
                                                       const float* __restrict__ shift) {
    constexpr int FV = F / 4;
    int idx  = blockIdx.x * 256 + threadIdx.x;
    int node = idx / FV;
    int fo   = (idx % FV) * 4;
    if (node >= NN) return;
    unsigned short* p = c + (size_t)node * LD + fo;
    uint2 v = *(uint2*)p;
    float a0 = bfl(v.x), a1 = bfh(v.x), a2 = bfl(v.y), a3 = bfh(v.y);
    float4 sc = *(const float4*)(scale + fo);
    float4 sh = *(const float4*)(shift + fo);
    a0 = fmaf(a0, sc.x, sh.x);
    a1 = fmaf(a1, sc.y, sh.y);
    a2 = fmaf(a2, sc.z, sh.z);
    a3 = fmaf(a3, sc.w, sh.w);
    v.x = pack2(a0, a1); v.y = pack2(a2, a3);
    *(uint2*)p = v;
}

// BN apply on c1 (F=256): bf16 back to Jh AND e4m3 copy for conv2's gather
__global__ __launch_bounds__(256) void bn_apply_fp8_kernel(unsigned short* __restrict__ c,
                                                           unsigned char* __restrict__ c8,
                                                           const float* __restrict__ scale,
                                                           const float* __restrict__ shift) {
    int idx  = blockIdx.x * 256 + threadIdx.x;
    int node = idx >> 6;
    int fo   = (idx & 63) * 4;
    if (node >= NN) return;
    unsigned short* p = c + (size_t)node * LD + fo;
    uint2 v = *(uint2*)p;
    float a0 = bfl(v.x), a1 = bfh(v.x), a2 = bfl(v.y), a3 = bfh(v.y);
    float4 sc = *(const float4*)(scale + fo);
    float4 sh = *(const float4*)(shift + fo);
    a0 = fmaf(a0, sc.x, sh.x);
    a1 = fmaf(a1, sc.y, sh.y);
    a2 = fmaf(a2, sc.z, sh.z);
    a3 = fmaf(a3, sc.w, sh.w);
    v.x = pack2(a0, a1); v.y = pack2(a2, a3);
    *(uint2*)p = v;
    int w = __builtin_amdgcn_cvt_pk_fp8_f32(a0, a1, 0, false);
    w     = __builtin_amdgcn_cvt_pk_fp8_f32(a2, a3, w, true);
    *(unsigned int*)(c8 + (size_t)node * 256 + fo) = (unsigned int)w;
}

// ---------------- head GEMM via MFMA ----------------
__global__ __launch_bounds__(256) void head_mfma_kernel(const unsigned short* __restrict__ Jh,
                                                        const unsigned short* __restrict__ Wb,
                                                        const float* __restrict__ b,
                                                        float* __restrict__ out) {
    int wave = threadIdx.x >> 6;
    int lane = threadIdx.x & 63;
    int tile = blockIdx.x * 4 + wave;
    if (tile >= NT) return;
    int m = lane & 15;
    int q = lane >> 4;
    const unsigned short* arow  = Jh + (size_t)(tile * 16 + m) * LD + q * 8;
    const unsigned short* bbase = Wb + (size_t)lane * 8;
    f32x4 acc0 = {0.f, 0.f, 0.f, 0.f};
    f32x4 acc1 = {0.f, 0.f, 0.f, 0.f};
    #pragma unroll 5
    for (int kb = 0; kb < 30; kb++) {
        bf16x8 a  = *(const bf16x8*)(arow + kb * 32);
        bf16x8 b0 = *(const bf16x8*)(bbase + (size_t)kb * 512);
        bf16x8 b1 = *(const bf16x8*)(bbase + (size_t)(30 + kb) * 512);
        acc0 = __builtin_amdgcn_mfma_f32_16x16x32_bf16(a, b0, acc0, 0, 0, 0);
        acc1 = __builtin_amdgcn_mfma_f32_16x16x32_bf16(a, b1, acc1, 0, 0, 0);
    }
    int col = m;
    float b0 = b[col], b1 = b[16 + col];
    #pragma unroll
    for (int r = 0; r < 4; r++) {
        float* op = out + (size_t)(tile * 16 + q * 4 + r) * 32 + col;
        op[0]  = acc0[r] + b0;
        op[16] = acc1[r] + b1;
    }
}

// ---------------- launch ----------------

extern "C" void kernel_launch(void* const* d_in, const int* in_sizes, int n_in,
                              void* d_out, int out_size, void* d_ws, size_t ws_size,
                              hipStream_t stream) {
    const float* x      = (const float*)d_in[0];
    const int*   e1_row = (const int*)d_in[1];
    const int*   e1_col = (const int*)d_in[2];
    const float* e1_val = (const float*)d_in[3];
    const int*   e2_row = (const int*)d_in[4];
    const int*   e2_col = (const int*)d_in[5];
    const float* e2_val = (const float*)d_in[6];
    const float* W_emb  = (const float*)d_in[7];
    const float* b_emb  = (const float*)d_in[8];
    const float* bn0_g  = (const float*)d_in[9];
    const float* bn0_b  = (const float*)d_in[10];
    const float* bn1_g  = (const float*)d_in[11];
    const float* bn1_b  = (const float*)d_in[12];
    const float* W_head = (const float*)d_in[13];
    const float* b_head = (const float*)d_in[14];
    float* out = (float*)d_out;

    char* ws = (char*)d_ws;
    auto alloc = [&](size_t bytes) -> char* {
        char* p = ws;
        ws += (bytes + 255) & ~(size_t)255;
        return p;
    };
    int*   rp1   = (int*)alloc((NN + 1) * 4);
    int*   cur1  = (int*)alloc(NN * 4);
    int*   rp2   = (int*)alloc((NN + 1) * 4);
    int*   cur2  = (int*)alloc(NN * 4);
    unsigned int* Ed1 = (unsigned int*)alloc((size_t)E1N * 4);
    unsigned int* Ed2 = (unsigned int*)alloc((size_t)E2N * 4);
    float* stats = (float*)alloc(1536 * 4);
    unsigned short* Wbh  = (unsigned short*)alloc(3840 * 8 * 2);
    unsigned short* Wbe  = (unsigned short*)alloc(2048 * 8 * 2);
    unsigned char*  C1f8 = (unsigned char*)alloc((size_t)NN * 256);
    unsigned short* Jh   = (unsigned short*)alloc((size_t)NN * LD * 2);

    float* sum0   = stats;        float* sq0    = stats + 128;
    float* sum1   = stats + 256;  float* sq1    = stats + 512;
    float* scale0 = stats + 768;  float* shift0 = stats + 896;
    float* scale1 = stats + 1024; float* shift1 = stats + 1280;

    const int EB = (E1N + E2N + 255) / 256;

    // CSR build + weight packs
    zero_kernel<<<(NN + 255) / 256, 256, 0, stream>>>(cur1, NN, cur2, NN, stats, 768);
    hist_kernel<<<EB, 256, 0, stream>>>(e1_row, e2_row, cur1, cur2);
    scan_kernel<<<2, 1024, 0, stream>>>(cur1, rp1, cur2, rp2);
    scatter_kernel<<<EB, 256, 0, stream>>>(e1_row, e1_col, e1_val, e2_row, e2_col, e2_val,
                                           cur1, Ed1, cur2, Ed2);
    packw_kernel<<<15, 256, 0, stream>>>(W_head, Wbh, 32, 30, 3840);
    packw_kernel<<<8, 256, 0, stream>>>(W_emb, Wbe, 64, 8, 2048);

    // embed -> Jh[:,0:64) (MFMA)
    embed_mfma_kernel<<<(NT + 3) / 4, 256, 0, stream>>>(x, Wbe, b_emb, Jh);

    // conv0 -> Jh[:,64:192), then BN
    spmm_bf16_kernel<16><<<2 * (NN / 16), 256, 0, stream>>>(rp1, Ed1, rp2, Ed2, Jh, Jh + 64);
    bn_stats_kernel<128><<<512, 256, 0, stream>>>(Jh + 64, sum0, sq0);
    bn_finalize_kernel<<<1, 128, 0, stream>>>(sum0, sq0, bn0_g, bn0_b, scale0, shift0, 128);
    bn_apply_kernel<128><<<(NN * 32 + 255) / 256, 256, 0, stream>>>(Jh + 64, scale0, shift0);

    // conv1 -> Jh[:,192:448), then BN + fp8 copy
    spmm_bf16_kernel<32><<<2 * (NN / 8), 256, 0, stream>>>(rp1, Ed1, rp2, Ed2, Jh + 64, Jh + 192);
    bn_stats_kernel<256><<<512, 256, 0, stream>>>(Jh + 192, sum1, sq1);
    bn_finalize_kernel<<<1, 256, 0, stream>>>(sum1, sq1, bn1_g, bn1_b, scale1, shift1, 256);
    bn_apply_fp8_kernel<<<(NN * 64 + 255) / 256, 256, 0, stream>>>(Jh + 192, C1f8, scale1, shift1);

    // conv2 -> Jh[:,448:960) (fp8 src)
    spmm_fp8_kernel<<<2 * (NN / 4), 256, 0, stream>>>(rp1, Ed1, rp2, Ed2, C1f8, Jh + 448);

    // head (MFMA)
    head_mfma_kernel<<<(NT + 3) / 4, 256, 0, stream>>>(Jh, Wbh, b_head, out);
}

// Round 9
// 815.331 us; speedup vs baseline: 1.8393x; 1.0108x over previous
//
#include <hip/hip_runtime.h>

// H2GCN forward, bf16 activations in fused Jh[N,960]:
//   cols [0,64)=h [64,192)=c0 [192,448)=c1 [448,960)=c2.
// CSR build: hist -> scan -> direct scatter of packed 4B records (col<<16|bf16val).
//   Cursors PADDED to one per 64B line (stride 16 ints): r6/r8 showed scatter time
//   tracks the 2.4M atomics (not store count/bytes) -> per-line RMW chain was
//   16 counters x 24 hits = 384 serialized cross-XCD RMWs; padding cuts it to 24.
// conv0/conv1: pull-SPMM bf16 gather (8B/lane, multi-row waves), fp32 acc.
// conv2: pull-SPMM over fp8 e4m3 copy of BN'd c1 (half gather bytes).
// Embed + Head: MFMA 16x16x32 bf16, weights pre-packed to B-fragment layout.

#define NN  50000
#define E1N 800000
#define E2N 1600000
#define LD  960
#define NT  3125         // 16-node tiles
#define PAD 16           // ints per counter line (64 B)

typedef short bf16x8 __attribute__((ext_vector_type(8)));
typedef float f32x4  __attribute__((ext_vector_type(4)));
typedef float f32x2  __attribute__((ext_vector_type(2)));

__device__ __forceinline__ float bfl(unsigned int w) { return __uint_as_float(w << 16); }
__device__ __forceinline__ float bfh(unsigned int w) { return __uint_as_float(w & 0xFFFF0000u); }
__device__ __forceinline__ float bf2f(unsigned short u) { return __uint_as_float(((unsigned int)u) << 16); }
__device__ __forceinline__ unsigned short f2bf(float f) {         // RNE
    unsigned int u = __float_as_uint(f);
    u += 0x7FFFu + ((u >> 16) & 1u);
    return (unsigned short)(u >> 16);
}
__device__ __forceinline__ unsigned int pack2(float a, float b) {
    return (unsigned int)f2bf(a) | ((unsigned int)f2bf(b) << 16);
}

// ---------------- setup kernels ----------------

__global__ __launch_bounds__(256) void zero_kernel(int* a, int na, int* b, int nb, float* c, int nc) {
    int i = blockIdx.x * 256 + threadIdx.x;
    if (i < na) a[i] = 0;
    if (i < nb) b[i] = 0;
    if (i < nc) c[i] = 0.f;
}

__global__ __launch_bounds__(256) void hist_kernel(const int* __restrict__ r1, const int* __restrict__ r2,
                                                   int* h1, int* h2) {
    int i = blockIdx.x * 256 + threadIdx.x;
    if (i < E1N) atomicAdd(&h1[(size_t)r1[i] * PAD], 1);
    else if (i < E1N + E2N) atomicAdd(&h2[(size_t)r2[i - E1N] * PAD], 1);
}

__global__ __launch_bounds__(1024) void scan_kernel(int* hist1, int* rp1, int* hist2, int* rp2) {
    int* hist = blockIdx.x ? hist2 : hist1;
    int* rp   = blockIdx.x ? rp2   : rp1;
    const int t = threadIdx.x;
    const int CH = 49;
    int base = t * CH;
    int lim = NN - base; if (lim > CH) lim = CH; if (lim < 0) lim = 0;
    int lsum = 0;
    for (int j = 0; j < lim; j++) lsum += hist[(size_t)(base + j) * PAD];
    __shared__ int s[1024];
    s[t] = lsum;
    __syncthreads();
    for (int off = 1; off < 1024; off <<= 1) {
        int v = (t >= off) ? s[t - off] : 0;
        __syncthreads();
        s[t] += v;
        __syncthreads();
    }
    int run = s[t] - lsum;
    for (int j = 0; j < lim; j++) {
        int hv = hist[(size_t)(base + j) * PAD];
        rp[base + j] = run;
        hist[(size_t)(base + j) * PAD] = run;    // cursor init for scatter
        run += hv;
    }
    if (t == 0) rp[NN] = s[1023];
}

// direct scatter: one packed 4B record (col<<16 | bf16(val)) per edge
__global__ __launch_bounds__(256) void scatter_kernel(
        const int* __restrict__ r1, const int* __restrict__ c1, const float* __restrict__ v1,
        const int* __restrict__ r2, const int* __restrict__ c2, const float* __restrict__ v2,
        int* cur1, unsigned int* __restrict__ Ed1, int* cur2, unsigned int* __restrict__ Ed2) {
    int i = blockIdx.x * 256 + threadIdx.x;
    if (i < E1N) {
        int r = r1[i];
        unsigned int rec = ((unsigned)c1[i] << 16) | (unsigned)f2bf(v1[i]);
        int pos = atomicAdd(&cur1[(size_t)r * PAD], 1);
        Ed1[pos] = rec;
    } else if (i < E1N + E2N) {
        int k = i - E1N;
        int r = r2[k];
        unsigned int rec = ((unsigned)c2[k] << 16) | (unsigned)f2bf(v2[k]);
        int pos = atomicAdd(&cur2[(size_t)r * PAD], 1);
        Ed2[pos] = rec;
    }
}

// ---------------- weight -> bf16 B-fragment pack ----------------
__global__ __launch_bounds__(256) void packw_kernel(const float* __restrict__ W, unsigned short* __restrict__ Wb,
                                                    int NC, int kbs, int total) {
    int i = blockIdx.x * 256 + threadIdx.x;
    if (i >= total) return;
    int lane  = i & 63;
    int kb    = (i >> 6) % kbs;
    int ctile = i / (kbs * 64);
    int n  = ctile * 16 + (lane & 15);
    int k0 = kb * 32 + (lane >> 4) * 8;
    unsigned short v[8];
    #pragma unroll
    for (int j = 0; j < 8; j++) v[j] = f2bf(W[(k0 + j) * NC + n]);
    *(uint4*)(Wb + (size_t)i * 8) = *(uint4*)v;
}

// ---------------- embed via MFMA ----------------
__global__ __launch_bounds__(256) void embed_mfma_kernel(const float* __restrict__ x,
                                                         const unsigned short* __restrict__ Wb,
                                                         const float* __restrict__ bias,
                                                         unsigned short* __restrict__ Jh) {
    int wave = threadIdx.x >> 6;
    int lane = threadIdx.x & 63;
    int tile = blockIdx.x * 4 + wave;
    if (tile >= NT) return;
    int m = lane & 15;
    int q = lane >> 4;
    const float* xr = x + (size_t)(tile * 16 + m) * 256 + q * 8;
    const unsigned short* bbase = Wb + (size_t)lane * 8;
    f32x4 acc[4];
    #pragma unroll
    for (int ct = 0; ct < 4; ct++) acc[ct] = (f32x4){0.f, 0.f, 0.f, 0.f};
    #pragma unroll
    for (int kb = 0; kb < 8; kb++) {
        float4 xa = *(const float4*)(xr + kb * 32);
        float4 xb = *(const float4*)(xr + kb * 32 + 4);
        unsigned short av[8];
        av[0] = f2bf(xa.x); av[1] = f2bf(xa.y); av[2] = f2bf(xa.z); av[3] = f2bf(xa.w);
        av[4] = f2bf(xb.x); av[5] = f2bf(xb.y); av[6] = f2bf(xb.z); av[7] = f2bf(xb.w);
        bf16x8 a = *(bf16x8*)av;
        #pragma unroll
        for (int ct = 0; ct < 4; ct++) {
            bf16x8 bfr = *(const bf16x8*)(bbase + (size_t)(ct * 8 + kb) * 512);
            acc[ct] = __builtin_amdgcn_mfma_f32_16x16x32_bf16(a, bfr, acc[ct], 0, 0, 0);
        }
    }
    #pragma unroll
    for (int ct = 0; ct < 4; ct++) {
        int col = ct * 16 + m;
        float bb = bias[col];
        #pragma unroll
        for (int r = 0; r < 4; r++) {
            float v = fmaxf(acc[ct][r] + bb, 0.f);
            Jh[(size_t)(tile * 16 + q * 4 + r) * LD + col] = f2bf(v);
        }
    }
}

// ---------------- pull SPMM, bf16 source, LPR lanes per row (4 feats/lane) ----------------
template <int LPR>
__global__ __launch_bounds__(256) void spmm_bf16_kernel(
        const int* __restrict__ rp1, const unsigned int* __restrict__ ed1,
        const int* __restrict__ rp2, const unsigned int* __restrict__ ed2,
        const unsigned short* __restrict__ src,   // Jh + src col offset, SRCF wide
        unsigned short* __restrict__ dst) {       // Jh + dst col offset (graph1 base)
    constexpr int ROWS = 64 / LPR;
    constexpr int SRCF = LPR * 4;
    constexpr int GB   = NN / (ROWS * 4);
    int g    = (blockIdx.x >= GB) ? 1 : 0;
    int bx   = blockIdx.x - g * GB;
    int wave = threadIdx.x >> 6;
    int lane = threadIdx.x & 63;
    int grp  = lane / LPR;
    int sub  = lane % LPR;
    int row  = (bx * 4 + wave) * ROWS + grp;
    const int*          rp = g ? rp2 : rp1;
    const unsigned int* ed = g ? ed2 : ed1;
    int beg = rp[row], end = rp[row + 1];

    float acc[4] = {0.f, 0.f, 0.f, 0.f};
    const unsigned short* sbase = src + sub * 4;

    int j = beg;
    for (; j + 8 <= end; j += 8) {
        unsigned int e[8];
        #pragma unroll
        for (int u = 0; u < 8; u++) e[u] = ed[j + u];
        uint2 s[8];
        #pragma unroll
        for (int u = 0; u < 8; u++) s[u] = *(const uint2*)(sbase + (size_t)(e[u] >> 16) * LD);
        #pragma unroll
        for (int u = 0; u < 8; u++) {
            float v = bfl(e[u]);
            acc[0]=fmaf(v,bfl(s[u].x),acc[0]); acc[1]=fmaf(v,bfh(s[u].x),acc[1]);
            acc[2]=fmaf(v,bfl(s[u].y),acc[2]); acc[3]=fmaf(v,bfh(s[u].y),acc[3]);
        }
    }
    for (; j < end; j++) {
        unsigned int e = ed[j];
        float v = bfl(e);
        uint2 s = *(const uint2*)(sbase + (size_t)(e >> 16) * LD);
        acc[0]=fmaf(v,bfl(s.x),acc[0]); acc[1]=fmaf(v,bfh(s.x),acc[1]);
        acc[2]=fmaf(v,bfl(s.y),acc[2]); acc[3]=fmaf(v,bfh(s.y),acc[3]);
    }

    unsigned short* dp = dst + (size_t)row * LD + g * SRCF + sub * 4;
    uint2 o; o.x = pack2(acc[0], acc[1]); o.y = pack2(acc[2], acc[3]);
    *(uint2*)dp = o;
}

// ---------------- pull SPMM, fp8 e4m3 source (conv2): 64 lanes x 4 fp8 ----------------
__global__ __launch_bounds__(256) void spmm_fp8_kernel(
        const int* __restrict__ rp1, const unsigned int* __restrict__ ed1,
        const int* __restrict__ rp2, const unsigned int* __restrict__ ed2,
        const unsigned char* __restrict__ src8,   // C1f8[N,256] e4m3
        unsigned short* __restrict__ dst) {       // Jh + 448
    constexpr int GB = NN / 4;
    int g    = (blockIdx.x >= GB) ? 1 : 0;
    int bx   = blockIdx.x - g * GB;
    int wave = threadIdx.x >> 6;
    int lane = threadIdx.x & 63;
    int row  = bx * 4 + wave;
    const int*          rp = g ? rp2 : rp1;
    const unsigned int* ed = g ? ed2 : ed1;
    int beg = rp[row], end = rp[row + 1];

    float acc[4] = {0.f, 0.f, 0.f, 0.f};
    const unsigned char* sbase = src8 + lane * 4;

    int j = beg;
    for (; j + 8 <= end; j += 8) {
        unsigned int e[8];
        #pragma unroll
        for (int u = 0; u < 8; u++) e[u] = ed[j + u];
        unsigned int s[8];
        #pragma unroll
        for (int u = 0; u < 8; u++) s[u] = *(const unsigned int*)(sbase + (size_t)(e[u] >> 16) * 256);
        #pragma unroll
        for (int u = 0; u < 8; u++) {
            float v = bfl(e[u]);
            f32x2 lo = __builtin_amdgcn_cvt_pk_f32_fp8(s[u], false);
            f32x2 hi = __builtin_amdgcn_cvt_pk_f32_fp8(s[u], true);
            acc[0]=fmaf(v,lo[0],acc[0]); acc[1]=fmaf(v,lo[1],acc[1]);
            acc[2]=fmaf(v,hi[0],acc[2]); acc[3]=fmaf(v,hi[1],acc[3]);
        }
    }
    for (; j < end; j++) {
        unsigned int e = ed[j];
        float v = bfl(e);
        unsigned int s = *(const unsigned int*)(sbase + (size_t)(e >> 16) * 256);
        f32x2 lo = __builtin_amdgcn_cvt_pk_f32_fp8(s, false);
        f32x2 hi = __builtin_amdgcn_cvt_pk_f32_fp8(s, true);
        acc[0]=fmaf(v,lo[0],acc[0]); acc[1]=fmaf(v,lo[1],acc[1]);
        acc[2]=fmaf(v,hi[0],acc[2]); acc[3]=fmaf(v,hi[1],acc[3]);
    }

    unsigned short* dp = dst + (size_t)row * LD + g * 256 + lane * 4;
    uint2 o; o.x = pack2(acc[0], acc[1]); o.y = pack2(acc[2], acc[3]);
    *(uint2*)dp = o;
}

// ---------------- BN stats / finalize / apply ----------------
template <int F>
__global__ __launch_bounds__(256) void bn_stats_kernel(const unsigned short* __restrict__ c,
                                                       float* sum, float* sumsq) {
    constexpr int SL = 256 / F;
    int f  = threadIdx.x % F;
    int sl = threadIdx.x / F;
    float s = 0.f, ss = 0.f;
    for (int r = blockIdx.x * SL + sl; r < NN; r += gridDim.x * SL) {
        float v = bf2f(c[(size_t)r * LD + f]);
        s += v; ss += v * v;
    }
    __shared__ float ls[256], lss[256];
    ls[threadIdx.x] = s; lss[threadIdx.x] = ss;
    __syncthreads();
    if (sl == 0) {
        #pragma unroll
        for (int u = 1; u < SL; u++) { s += ls[f + u * F]; ss += lss[f + u * F]; }
        atomicAdd(&sum[f], s);
        atomicAdd(&sumsq[f], ss);
    }
}

__global__ void bn_finalize_kernel(const float* sum, const float* sumsq, const float* __restrict__ gamma,
                                   const float* __restrict__ beta, float* scale, float* shift, int F) {
    int f = blockIdx.x * blockDim.x + threadIdx.x;
    if (f >= F) return;
    float m   = sum[f] * (1.0f / NN);
    float var = sumsq[f] * (1.0f / NN) - m * m;
    float sc  = gamma[f] * rsqrtf(var + 1e-5f);
    scale[f] = sc;
    shift[f] = beta[f] - m * sc;
}

template <int F>
__global__ __launch_bounds__(256) void bn_apply_kernel(unsigned short* __restrict__ c,
                                                       const float* __restrict__ scale,
                                                       const float* __restrict__ shift) {
    constexpr int FV = F / 4;
    int idx  = blockIdx.x * 256 + threadIdx.x;
    int node = idx / FV;
    int fo   = (idx % FV) * 4;
    if (node >= NN) return;
    unsigned short* p = c + (size_t)node * LD + fo;
    uint2 v = *(uint2*)p;
    float a0 = bfl(v.x), a1 = bfh(v.x), a2 = bfl(v.y), a3 = bfh(v.y);
    float4 sc = *(const float4*)(scale + fo);
    float4 sh = *(const float4*)(shift + fo);
    a0 = fmaf(a0, sc.x, sh.x);
    a1 = fmaf(a1, sc.y, sh.y);
    a2 = fmaf(a2, sc.z, sh.z);
    a3 = fmaf(a3, sc.w, sh.w);
    v.x = pack2(a0, a1); v.y = pack2(a2, a3);
    *(uint2*)p = v;
}

// BN apply on c1 (F=256): bf16 back to Jh AND e4m3 copy for conv2's gather
__global__ __launch_bounds__(256) void bn_apply_fp8_kernel(unsigned short* __restrict__ c,
                                                           unsigned char* __restrict__ c8,
                                                           const float* __restrict__ scale,
                                                           const float* __restrict__ shift) {
    int idx  = blockIdx.x * 256 + threadIdx.x;
    int node = idx >> 6;
    int fo   = (idx & 63) * 4;
    if (node >= NN) return;
    unsigned short* p = c + (size_t)node * LD + fo;
    uint2 v = *(uint2*)p;
    float a0 = bfl(v.x), a1 = bfh(v.x), a2 = bfl(v.y), a3 = bfh(v.y);
    float4 sc = *(const float4*)(scale + fo);
    float4 sh = *(const float4*)(shift + fo);
    a0 = fmaf(a0, sc.x, sh.x);
    a1 = fmaf(a1, sc.y, sh.y);
    a2 = fmaf(a2, sc.z, sh.z);
    a3 = fmaf(a3, sc.w, sh.w);
    v.x = pack2(a0, a1); v.y = pack2(a2, a3);
    *(uint2*)p = v;
    int w = __builtin_amdgcn_cvt_pk_fp8_f32(a0, a1, 0, false);
    w     = __builtin_amdgcn_cvt_pk_fp8_f32(a2, a3, w, true);
    *(unsigned int*)(c8 + (size_t)node * 256 + fo) = (unsigned int)w;
}

// ---------------- head GEMM via MFMA ----------------
__global__ __launch_bounds__(256) void head_mfma_kernel(const unsigned short* __restrict__ Jh,
                                                        const unsigned short* __restrict__ Wb,
                                                        const float* __restrict__ b,
                                                        float* __restrict__ out) {
    int wave = threadIdx.x >> 6;
    int lane = threadIdx.x & 63;
    int tile = blockIdx.x * 4 + wave;
    if (tile >= NT) return;
    int m = lane & 15;
    int q = lane >> 4;
    const unsigned short* arow  = Jh + (size_t)(tile * 16 + m) * LD + q * 8;
    const unsigned short* bbase = Wb + (size_t)lane * 8;
    f32x4 acc0 = {0.f, 0.f, 0.f, 0.f};
    f32x4 acc1 = {0.f, 0.f, 0.f, 0.f};
    #pragma unroll 5
    for (int kb = 0; kb < 30; kb++) {
        bf16x8 a  = *(const bf16x8*)(arow + kb * 32);
        bf16x8 b0 = *(const bf16x8*)(bbase + (size_t)kb * 512);
        bf16x8 b1 = *(const bf16x8*)(bbase + (size_t)(30 + kb) * 512);
        acc0 = __builtin_amdgcn_mfma_f32_16x16x32_bf16(a, b0, acc0, 0, 0, 0);
        acc1 = __builtin_amdgcn_mfma_f32_16x16x32_bf16(a, b1, acc1, 0, 0, 0);
    }
    int col = m;
    float b0 = b[col], b1 = b[16 + col];
    #pragma unroll
    for (int r = 0; r < 4; r++) {
        float* op = out + (size_t)(tile * 16 + q * 4 + r) * 32 + col;
        op[0]  = acc0[r] + b0;
        op[16] = acc1[r] + b1;
    }
}

// ---------------- launch ----------------

extern "C" void kernel_launch(void* const* d_in, const int* in_sizes, int n_in,
                              void* d_out, int out_size, void* d_ws, size_t ws_size,
                              hipStream_t stream) {
    const float* x      = (const float*)d_in[0];
    const int*   e1_row = (const int*)d_in[1];
    const int*   e1_col = (const int*)d_in[2];
    const float* e1_val = (const float*)d_in[3];
    const int*   e2_row = (const int*)d_in[4];
    const int*   e2_col = (const int*)d_in[5];
    const float* e2_val = (const float*)d_in[6];
    const float* W_emb  = (const float*)d_in[7];
    const float* b_emb  = (const float*)d_in[8];
    const float* bn0_g  = (const float*)d_in[9];
    const float* bn0_b  = (const float*)d_in[10];
    const float* bn1_g  = (const float*)d_in[11];
    const float* bn1_b  = (const float*)d_in[12];
    const float* W_head = (const float*)d_in[13];
    const float* b_head = (const float*)d_in[14];
    float* out = (float*)d_out;

    char* ws = (char*)d_ws;
    auto alloc = [&](size_t bytes) -> char* {
        char* p = ws;
        ws += (bytes + 255) & ~(size_t)255;
        return p;
    };
    int*   rp1   = (int*)alloc((NN + 1) * 4);
    int*   cur1  = (int*)alloc((size_t)NN * PAD * 4);   // padded hist/cursor
    int*   rp2   = (int*)alloc((NN + 1) * 4);
    int*   cur2  = (int*)alloc((size_t)NN * PAD * 4);   // padded hist/cursor
    unsigned int* Ed1 = (unsigned int*)alloc((size_t)E1N * 4);
    unsigned int* Ed2 = (unsigned int*)alloc((size_t)E2N * 4);
    float* stats = (float*)alloc(1536 * 4);
    unsigned short* Wbh  = (unsigned short*)alloc(3840 * 8 * 2);
    unsigned short* Wbe  = (unsigned short*)alloc(2048 * 8 * 2);
    unsigned char*  C1f8 = (unsigned char*)alloc((size_t)NN * 256);
    unsigned short* Jh   = (unsigned short*)alloc((size_t)NN * LD * 2);

    float* sum0   = stats;        float* sq0    = stats + 128;
    float* sum1   = stats + 256;  float* sq1    = stats + 512;
    float* scale0 = stats + 768;  float* shift0 = stats + 896;
    float* scale1 = stats + 1024; float* shift1 = stats + 1280;

    const int EB = (E1N + E2N + 255) / 256;

    // CSR build + weight packs
    zero_kernel<<<(NN * PAD + 255) / 256, 256, 0, stream>>>(cur1, NN * PAD, cur2, NN * PAD, stats, 768);
    hist_kernel<<<EB, 256, 0, stream>>>(e1_row, e2_row, cur1, cur2);
    scan_kernel<<<2, 1024, 0, stream>>>(cur1, rp1, cur2, rp2);
    scatter_kernel<<<EB, 256, 0, stream>>>(e1_row, e1_col, e1_val, e2_row, e2_col, e2_val,
                                           cur1, Ed1, cur2, Ed2);
    packw_kernel<<<15, 256, 0, stream>>>(W_head, Wbh, 32, 30, 3840);
    packw_kernel<<<8, 256, 0, stream>>>(W_emb, Wbe, 64, 8, 2048);

    // embed -> Jh[:,0:64) (MFMA)
    embed_mfma_kernel<<<(NT + 3) / 4, 256, 0, stream>>>(x, Wbe, b_emb, Jh);

    // conv0 -> Jh[:,64:192), then BN
    spmm_bf16_kernel<16><<<2 * (NN / 16), 256, 0, stream>>>(rp1, Ed1, rp2, Ed2, Jh, Jh + 64);
    bn_stats_kernel<128><<<512, 256, 0, stream>>>(Jh + 64, sum0, sq0);
    bn_finalize_kernel<<<1, 128, 0, stream>>>(sum0, sq0, bn0_g, bn0_b, scale0, shift0, 128);
    bn_apply_kernel<128><<<(NN * 32 + 255) / 256, 256, 0, stream>>>(Jh + 64, scale0, shift0);

    // conv1 -> Jh[:,192:448), then BN + fp8 copy
    spmm_bf16_kernel<32><<<2 * (NN / 8), 256, 0, stream>>>(rp1, Ed1, rp2, Ed2, Jh + 64, Jh + 192);
    bn_stats_kernel<256><<<512, 256, 0, stream>>>(Jh + 192, sum1, sq1);
    bn_finalize_kernel<<<1, 256, 0, stream>>>(sum1, sq1, bn1_g, bn1_b, scale1, shift1, 256);
    bn_apply_fp8_kernel<<<(NN * 64 + 255) / 256, 256, 0, stream>>>(Jh + 192, C1f8, scale1, shift1);

    // conv2 -> Jh[:,448:960) (fp8 src)
    spmm_fp8_kernel<<<2 * (NN / 4), 256, 0, stream>>>(rp1, Ed1, rp2, Ed2, C1f8, Jh + 448);

    // head (MFMA)
    head_mfma_kernel<<<(NT + 3) / 4, 256, 0, stream>>>(Jh, Wbh, b_head, out);
}

// Round 10
// 554.182 us; speedup vs baseline: 2.7060x; 1.4712x over previous
//
#include <hip/hip_runtime.h>

// H2GCN forward, bf16 activations in fused Jh[N,960]:
//   cols [0,64)=h [64,192)=c0 [192,448)=c1 [448,960)=c2.
// CSR build = two-level LDS counting sort (no global atomics, block-local writes):
//   K1 bucket_count: per-block per-128-row-bucket LDS counts -> bc[blk][391]
//   K2 bucket_scan:  bucket bases + per-(block,bucket) running bases (1 block)
//   K3 bucket_place: re-read edges, LDS cursors -> 8B records in ~168B runs
//   K5 bucket_sort:  per-bucket LDS count/prefix -> writes rp[] AND packed 4B Ed
//   (r6-r9 showed direct scatter is line-amplification-bound: 16 stores/line from
//    ~16 blocks on 8 XCDs -> 155MB HBM writes; block-local windows let L2 merge.)
// conv0/conv1: pull-SPMM bf16 gather (8B/lane, multi-row waves), fp32 acc.
// conv2: pull-SPMM over fp8 e4m3 copy of BN'd c1 (half gather bytes).
// Embed + Head: MFMA 16x16x32 bf16, weights pre-packed to B-fragment layout.

#define NN  50000
#define E1N 800000
#define E2N 1600000
#define LD  960
#define NT  3125         // 16-node tiles
#define NBKT 391         // 128-row buckets: ceil(50000/128)
#define CHUNK 8192
#define G1B 98           // ceil(E1N/CHUNK)
#define G2B 196          // ceil(E2N/CHUNK)

typedef short bf16x8 __attribute__((ext_vector_type(8)));
typedef float f32x4  __attribute__((ext_vector_type(4)));
typedef float f32x2  __attribute__((ext_vector_type(2)));

__device__ __forceinline__ float bfl(unsigned int w) { return __uint_as_float(w << 16); }
__device__ __forceinline__ float bfh(unsigned int w) { return __uint_as_float(w & 0xFFFF0000u); }
__device__ __forceinline__ float bf2f(unsigned short u) { return __uint_as_float(((unsigned int)u) << 16); }
__device__ __forceinline__ unsigned short f2bf(float f) {         // RNE
    unsigned int u = __float_as_uint(f);
    u += 0x7FFFu + ((u >> 16) & 1u);
    return (unsigned short)(u >> 16);
}
__device__ __forceinline__ unsigned int pack2(float a, float b) {
    return (unsigned int)f2bf(a) | ((unsigned int)f2bf(b) << 16);
}

// ---------------- CSR build ----------------

__global__ __launch_bounds__(256) void zero_kernel(float* c, int nc) {
    int i = blockIdx.x * 256 + threadIdx.x;
    if (i < nc) c[i] = 0.f;
}

// K1: per-block bucket counts (LDS only)
__global__ __launch_bounds__(256) void bucket_count_kernel(const int* __restrict__ r1,
                                                           const int* __restrict__ r2,
                                                           int* __restrict__ bc1, int* __restrict__ bc2) {
    __shared__ int cnt[NBKT];
    for (int t = threadIdx.x; t < NBKT; t += 256) cnt[t] = 0;
    __syncthreads();
    int blk = blockIdx.x;
    const int* r; int base, lim; int* bc;
    if (blk < G1B) { r = r1; base = blk * CHUNK; lim = min(base + CHUNK, E1N); bc = bc1 + blk * NBKT; }
    else { int b2 = blk - G1B; r = r2; base = b2 * CHUNK; lim = min(base + CHUNK, E2N); bc = bc2 + b2 * NBKT; }
    for (int i = base + threadIdx.x; i < lim; i += 256)
        atomicAdd(&cnt[r[i] >> 7], 1);
    __syncthreads();
    for (int t = threadIdx.x; t < NBKT; t += 256) bc[t] = cnt[t];
}

// K2: bucket totals -> bucket bases; rewrite bc to per-(block,bucket) absolute bases.
// After this, bc[0*NBKT + t] == bucket t's base (used as bb by K5).
__global__ __launch_bounds__(512) void bucket_scan_kernel(int* __restrict__ bc1, int* __restrict__ bc2) {
    __shared__ int s[512];
    int t = threadIdx.x;
    int tot1 = 0, tot2 = 0;
    if (t < NBKT) {
        for (int b = 0; b < G1B; b++) tot1 += bc1[b * NBKT + t];
        for (int b = 0; b < G2B; b++) tot2 += bc2[b * NBKT + t];
    }
    s[t] = (t < NBKT) ? tot1 : 0;
    __syncthreads();
    for (int off = 1; off < 512; off <<= 1) {
        int v = (t >= off) ? s[t - off] : 0;
        __syncthreads(); s[t] += v; __syncthreads();
    }
    int base1 = ((t < NBKT) ? s[t] : 0) - tot1;
    __syncthreads();
    s[t] = (t < NBKT) ? tot2 : 0;
    __syncthreads();
    for (int off = 1; off < 512; off <<= 1) {
        int v = (t >= off) ? s[t - off] : 0;
        __syncthreads(); s[t] += v; __syncthreads();
    }
    int base2 = ((t < NBKT) ? s[t] : 0) - tot2;
    if (t < NBKT) {
        int run = base1;
        for (int b = 0; b < G1B; b++) { int v = bc1[b * NBKT + t]; bc1[b * NBKT + t] = run; run += v; }
        run = base2;
        for (int b = 0; b < G2B; b++) { int v = bc2[b * NBKT + t]; bc2[b * NBKT + t] = run; run += v; }
    }
}

// K3: place 8B records (x = col<<16|row, y = fp32 val) into bucket regions via LDS cursors
__global__ __launch_bounds__(256) void bucket_place_kernel(
        const int* __restrict__ r1, const int* __restrict__ c1, const float* __restrict__ v1,
        const int* __restrict__ r2, const int* __restrict__ c2, const float* __restrict__ v2,
        const int* __restrict__ bc1, const int* __restrict__ bc2,
        uint2* __restrict__ T1, uint2* __restrict__ T2) {
    __shared__ int pos[NBKT];
    int blk = blockIdx.x;
    const int *r, *c; const float* v; int base, lim; const int* bc; uint2* T;
    if (blk < G1B) { r = r1; c = c1; v = v1; base = blk * CHUNK; lim = min(base + CHUNK, E1N);
                     bc = bc1 + blk * NBKT; T = T1; }
    else { int b2 = blk - G1B; r = r2; c = c2; v = v2; base = b2 * CHUNK; lim = min(base + CHUNK, E2N);
           bc = bc2 + b2 * NBKT; T = T2; }
    for (int t = threadIdx.x; t < NBKT; t += 256) pos[t] = bc[t];
    __syncthreads();
    for (int i = base + threadIdx.x; i < lim; i += 256) {
        int row = r[i];
        int p = atomicAdd(&pos[row >> 7], 1);
        T[p] = make_uint2(((unsigned)c[i] << 16) | (unsigned)row, __float_as_uint(v[i]));
    }
}

// K5: per-bucket LDS counting sort -> rp[] + packed 4B Ed (col<<16|bf16val)
__global__ __launch_bounds__(256) void bucket_sort_kernel(
        const int* __restrict__ bb1, const uint2* __restrict__ T1, int* __restrict__ rp1, unsigned int* __restrict__ Ed1,
        const int* __restrict__ bb2, const uint2* __restrict__ T2, int* __restrict__ rp2, unsigned int* __restrict__ Ed2) {
    int b = blockIdx.x % NBKT;
    int g = blockIdx.x / NBKT;
    const int* bb = g ? bb2 : bb1;       // bb[t] = bc[0][t] = bucket base
    const uint2* T = g ? T2 : T1;
    int* rp = g ? rp2 : rp1;
    unsigned int* Ed = g ? Ed2 : Ed1;
    int EN = g ? E2N : E1N;
    int beg = bb[b];
    int end = (b == NBKT - 1) ? EN : bb[b + 1];
    int R0 = b * 128;
    int nrows = min(128, NN - R0);
    __shared__ int cnt[129];
    __shared__ int cur[128];
    for (int t = threadIdx.x; t < 129; t += 256) cnt[t] = 0;
    __syncthreads();
    for (int i = beg + threadIdx.x; i < end; i += 256)
        atomicAdd(&cnt[((T[i].x & 0xFFFFu) & 127) + 1], 1);
    __syncthreads();
    for (int off = 1; off < 129; off <<= 1) {          // inclusive scan -> cnt[r] = exclusive prefix of row r
        int v = 0;
        if (threadIdx.x < 129 && (int)threadIdx.x >= off) v = cnt[threadIdx.x - off];
        __syncthreads();
        if (threadIdx.x < 129) cnt[threadIdx.x] += v;
        __syncthreads();
    }
    if ((int)threadIdx.x < nrows) {
        int p = beg + cnt[threadIdx.x];
        cur[threadIdx.x] = p;
        rp[R0 + threadIdx.x] = p;
    }
    if (b == NBKT - 1 && threadIdx.x == 0) rp[NN] = end;
    __syncthreads();
    for (int i = beg + threadIdx.x; i < end; i += 256) {
        uint2 rec = T[i];
        int rl = (rec.x & 0xFFFFu) & 127;
        int p = atomicAdd(&cur[rl], 1);
        Ed[p] = (rec.x & 0xFFFF0000u) | (unsigned)f2bf(__uint_as_float(rec.y));
    }
}

// ---------------- weight -> bf16 B-fragment pack ----------------
__global__ __launch_bounds__(256) void packw_kernel(const float* __restrict__ W, unsigned short* __restrict__ Wb,
                                                    int NC, int kbs, int total) {
    int i = blockIdx.x * 256 + threadIdx.x;
    if (i >= total) return;
    int lane  = i & 63;
    int kb    = (i >> 6) % kbs;
    int ctile = i / (kbs * 64);
    int n  = ctile * 16 + (lane & 15);
    int k0 = kb * 32 + (lane >> 4) * 8;
    unsigned short v[8];
    #pragma unroll
    for (int j = 0; j < 8; j++) v[j] = f2bf(W[(k0 + j) * NC + n]);
    *(uint4*)(Wb + (size_t)i * 8) = *(uint4*)v;
}

// ---------------- embed via MFMA ----------------
__global__ __launch_bounds__(256) void embed_mfma_kernel(const float* __restrict__ x,
                                                         const unsigned short* __restrict__ Wb,
                                                         const float* __restrict__ bias,
                                                         unsigned short* __restrict__ Jh) {
    int wave = threadIdx.x >> 6;
    int lane = threadIdx.x & 63;
    int tile = blockIdx.x * 4 + wave;
    if (tile >= NT) return;
    int m = lane & 15;
    int q = lane >> 4;
    const float* xr = x + (size_t)(tile * 16 + m) * 256 + q * 8;
    const unsigned short* bbase = Wb + (size_t)lane * 8;
    f32x4 acc[4];
    #pragma unroll
    for (int ct = 0; ct < 4; ct++) acc[ct] = (f32x4){0.f, 0.f, 0.f, 0.f};
    #pragma unroll
    for (int kb = 0; kb < 8; kb++) {
        float4 xa = *(const float4*)(xr + kb * 32);
        float4 xb = *(const float4*)(xr + kb * 32 + 4);
        unsigned short av[8];
        av[0] = f2bf(xa.x); av[1] = f2bf(xa.y); av[2] = f2bf(xa.z); av[3] = f2bf(xa.w);
        av[4] = f2bf(xb.x); av[5] = f2bf(xb.y); av[6] = f2bf(xb.z); av[7] = f2bf(xb.w);
        bf16x8 a = *(bf16x8*)av;
        #pragma unroll
        for (int ct = 0; ct < 4; ct++) {
            bf16x8 bfr = *(const bf16x8*)(bbase + (size_t)(ct * 8 + kb) * 512);
            acc[ct] = __builtin_amdgcn_mfma_f32_16x16x32_bf16(a, bfr, acc[ct], 0, 0, 0);
        }
    }
    #pragma unroll
    for (int ct = 0; ct < 4; ct++) {
        int col = ct * 16 + m;
        float bb = bias[col];
        #pragma unroll
        for (int r = 0; r < 4; r++) {
            float v = fmaxf(acc[ct][r] + bb, 0.f);
            Jh[(size_t)(tile * 16 + q * 4 + r) * LD + col] = f2bf(v);
        }
    }
}

// ---------------- pull SPMM, bf16 source, LPR lanes per row (4 feats/lane) ----------------
template <int LPR>
__global__ __launch_bounds__(256) void spmm_bf16_kernel(
        const int* __restrict__ rp1, const unsigned int* __restrict__ ed1,
        const int* __restrict__ rp2, const unsigned int* __restrict__ ed2,
        const unsigned short* __restrict__ src,   // Jh + src col offset, SRCF wide
        unsigned short* __restrict__ dst) {       // Jh + dst col offset (graph1 base)
    constexpr int ROWS = 64 / LPR;
    constexpr int SRCF = LPR * 4;
    constexpr int GB   = NN / (ROWS * 4);
    int g    = (blockIdx.x >= GB) ? 1 : 0;
    int bx   = blockIdx.x - g * GB;
    int wave = threadIdx.x >> 6;
    int lane = threadIdx.x & 63;
    int grp  = lane / LPR;
    int sub  = lane % LPR;
    int row  = (bx * 4 + wave) * ROWS + grp;
    const int*          rp = g ? rp2 : rp1;
    const unsigned int* ed = g ? ed2 : ed1;
    int beg = rp[row], end = rp[row + 1];

    float acc[4] = {0.f, 0.f, 0.f, 0.f};
    const unsigned short* sbase = src + sub * 4;

    int j = beg;
    for (; j + 8 <= end; j += 8) {
        unsigned int e[8];
        #pragma unroll
        for (int u = 0; u < 8; u++) e[u] = ed[j + u];
        uint2 s[8];
        #pragma unroll
        for (int u = 0; u < 8; u++) s[u] = *(const uint2*)(sbase + (size_t)(e[u] >> 16) * LD);
        #pragma unroll
        for (int u = 0; u < 8; u++) {
            float v = bfl(e[u]);
            acc[0]=fmaf(v,bfl(s[u].x),acc[0]); acc[1]=fmaf(v,bfh(s[u].x),acc[1]);
            acc[2]=fmaf(v,bfl(s[u].y),acc[2]); acc[3]=fmaf(v,bfh(s[u].y),acc[3]);
        }
    }
    for (; j < end; j++) {
        unsigned int e = ed[j];
        float v = bfl(e);
        uint2 s = *(const uint2*)(sbase + (size_t)(e >> 16) * LD);
        acc[0]=fmaf(v,bfl(s.x),acc[0]); acc[1]=fmaf(v,bfh(s.x),acc[1]);
        acc[2]=fmaf(v,bfl(s.y),acc[2]); acc[3]=fmaf(v,bfh(s.y),acc[3]);
    }

    unsigned short* dp = dst + (size_t)row * LD + g * SRCF + sub * 4;
    uint2 o; o.x = pack2(acc[0], acc[1]); o.y = pack2(acc[2], acc[3]);
    *(uint2*)dp = o;
}

// ---------------- pull SPMM, fp8 e4m3 source (conv2): 64 lanes x 4 fp8 ----------------
__global__ __launch_bounds__(256) void spmm_fp8_kernel(
        const int* __restrict__ rp1, const unsigned int* __restrict__ ed1,
        const int* __restrict__ rp2, const unsigned int* __restrict__ ed2,
        const unsigned char* __restrict__ src8,   // C1f8[N,256] e4m3
        unsigned short* __restrict__ dst) {       // Jh + 448
    constexpr int GB = NN / 4;
    int g    = (blockIdx.x >= GB) ? 1 : 0;
    int bx   = blockIdx.x - g * GB;
    int wave = threadIdx.x >> 6;
    int lane = threadIdx.x & 63;
    int row  = bx * 4 + wave;
    const int*          rp = g ? rp2 : rp1;
    const unsigned int* ed = g ? ed2 : ed1;
    int beg = rp[row], end = rp[row + 1];

    float acc[4] = {0.f, 0.f, 0.f, 0.f};
    const unsigned char* sbase = src8 + lane * 4;

    int j = beg;
    for (; j + 8 <= end; j += 8) {
        unsigned int e[8];
        #pragma unroll
        for (int u = 0; u < 8; u++) e[u] = ed[j + u];
        unsigned int s[8];
        #pragma unroll
        for (int u = 0; u < 8; u++) s[u] = *(const unsigned int*)(sbase + (size_t)(e[u] >> 16) * 256);
        #pragma unroll
        for (int u = 0; u < 8; u++) {
            float v = bfl(e[u]);
            f32x2 lo = __builtin_amdgcn_cvt_pk_f32_fp8(s[u], false);
            f32x2 hi = __builtin_amdgcn_cvt_pk_f32_fp8(s[u], true);
            acc[0]=fmaf(v,lo[0],acc[0]); acc[1]=fmaf(v,lo[1],acc[1]);
            acc[2]=fmaf(v,hi[0],acc[2]); acc[3]=fmaf(v,hi[1],acc[3]);
        }
    }
    for (; j < end; j++) {
        unsigned int e = ed[j];
        float v = bfl(e);
        unsigned int s = *(const unsigned int*)(sbase + (size_t)(e >> 16) * 256);
        f32x2 lo = __builtin_amdgcn_cvt_pk_f32_fp8(s, false);
        f32x2 hi = __builtin_amdgcn_cvt_pk_f32_fp8(s, true);
        acc[0]=fmaf(v,lo[0],acc[0]); acc[1]=fmaf(v,lo[1],acc[1]);
        acc[2]=fmaf(v,hi[0],acc[2]); acc[3]=fmaf(v,hi[1],acc[3]);
    }

    unsigned short* dp = dst + (size_t)row * LD + g * 256 + lane * 4;
    uint2 o; o.x = pack2(acc[0], acc[1]); o.y = pack2(acc[2], acc[3]);
    *(uint2*)dp = o;
}

// ---------------- BN stats / finalize / apply ----------------
template <int F>
__global__ __launch_bounds__(256) void bn_stats_kernel(const unsigned short* __restrict__ c,
                                                       float* sum, float* sumsq) {
    constexpr int SL = 256 / F;
    int f  = threadIdx.x % F;
    int sl = threadIdx.x / F;
    float s = 0.f, ss = 0.f;
    for (int r = blockIdx.x * SL + sl; r < NN; r += gridDim.x * SL) {
        float v = bf2f(c[(size_t)r * LD + f]);
        s += v; ss += v * v;
    }
    __shared__ float ls[256], lss[256];
    ls[threadIdx.x] = s; lss[threadIdx.x] = ss;
    __syncthreads();
    if (sl == 0) {
        #pragma unroll
        for (int u = 1; u < SL; u++) { s += ls[f + u * F]; ss += lss[f + u * F]; }
        atomicAdd(&sum[f], s);
        atomicAdd(&sumsq[f], ss);
    }
}

__global__ void bn_finalize_kernel(const float* sum, const float* sumsq, const float* __restrict__ gamma,
                                   const float* __restrict__ beta, float* scale, float* shift, int F) {
    int f = blockIdx.x * blockDim.x + threadIdx.x;
    if (f >= F) return;
    float m   = sum[f] * (1.0f / NN);
    float var = sumsq[f] * (1.0f / NN) - m * m;
    float sc  = gamma[f] * rsqrtf(var + 1e-5f);
    scale[f] = sc;
    shift[f] = beta[f] - m * sc;
}

template <int F>
__global__ __launch_bounds__(256) void bn_apply_kernel(unsigned short* __restrict__ c,
                                                       const float* __restrict__ scale,
                                                       const float* __restrict__ shift) {
    constexpr int FV = F / 4;
    int idx  = blockIdx.x * 256 + threadIdx.x;
    int node = idx / FV;
    int fo   = (idx % FV) * 4;
    if (node >= NN) return;
    unsigned short* p = c + (size_t)node * LD + fo;
    uint2 v = *(uint2*)p;
    float a0 = bfl(v.x), a1 = bfh(v.x), a2 = bfl(v.y), a3 = bfh(v.y);
    float4 sc = *(const float4*)(scale + fo);
    float4 sh = *(const float4*)(shift + fo);
    a0 = fmaf(a0, sc.x, sh.x);
    a1 = fmaf(a1, sc.y, sh.y);
    a2 = fmaf(a2, sc.z, sh.z);
    a3 = fmaf(a3, sc.w, sh.w);
    v.x = pack2(a0, a1); v.y = pack2(a2, a3);
    *(uint2*)p = v;
}

// BN apply on c1 (F=256): bf16 back to Jh AND e4m3 copy for conv2's gather
__global__ __launch_bounds__(256) void bn_apply_fp8_kernel(unsigned short* __restrict__ c,
                                                           unsigned char* __restrict__ c8,
                                                           const float* __restrict__ scale,
                                                           const float* __restrict__ shift) {
    int idx  = blockIdx.x * 256 + threadIdx.x;
    int node = idx >> 6;
    int fo   = (idx & 63) * 4;
    if (node >= NN) return;
    unsigned short* p = c + (size_t)node * LD + fo;
    uint2 v = *(uint2*)p;
    float a0 = bfl(v.x), a1 = bfh(v.x), a2 = bfl(v.y), a3 = bfh(v.y);
    float4 sc = *(const float4*)(scale + fo);
    float4 sh = *(const float4*)(shift + fo);
    a0 = fmaf(a0, sc.x, sh.x);
    a1 = fmaf(a1, sc.y, sh.y);
    a2 = fmaf(a2, sc.z, sh.z);
    a3 = fmaf(a3, sc.w, sh.w);
    v.x = pack2(a0, a1); v.y = pack2(a2, a3);
    *(uint2*)p = v;
    int w = __builtin_amdgcn_cvt_pk_fp8_f32(a0, a1, 0, false);
    w     = __builtin_amdgcn_cvt_pk_fp8_f32(a2, a3, w, true);
    *(unsigned int*)(c8 + (size_t)node * 256 + fo) = (unsigned int)w;
}

// ---------------- head GEMM via MFMA ----------------
__global__ __launch_bounds__(256) void head_mfma_kernel(const unsigned short* __restrict__ Jh,
                                                        const unsigned short* __restrict__ Wb,
                                                        const float* __restrict__ b,
                                                        float* __restrict__ out) {
    int wave = threadIdx.x >> 6;
    int lane = threadIdx.x & 63;
    int tile = blockIdx.x * 4 + wave;
    if (tile >= NT) return;
    int m = lane & 15;
    int q = lane >> 4;
    const unsigned short* arow  = Jh + (size_t)(tile * 16 + m) * LD + q * 8;
    const unsigned short* bbase = Wb + (size_t)lane * 8;
    f32x4 acc0 = {0.f, 0.f, 0.f, 0.f};
    f32x4 acc1 = {0.f, 0.f, 0.f, 0.f};
    #pragma unroll 5
    for (int kb = 0; kb < 30; kb++) {
        bf16x8 a  = *(const bf16x8*)(arow + kb * 32);
        bf16x8 b0 = *(const bf16x8*)(bbase + (size_t)kb * 512);
        bf16x8 b1 = *(const bf16x8*)(bbase + (size_t)(30 + kb) * 512);
        acc0 = __builtin_amdgcn_mfma_f32_16x16x32_bf16(a, b0, acc0, 0, 0, 0);
        acc1 = __builtin_amdgcn_mfma_f32_16x16x32_bf16(a, b1, acc1, 0, 0, 0);
    }
    int col = m;
    float b0 = b[col], b1 = b[16 + col];
    #pragma unroll
    for (int r = 0; r < 4; r++) {
        float* op = out + (size_t)(tile * 16 + q * 4 + r) * 32 + col;
        op[0]  = acc0[r] + b0;
        op[16] = acc1[r] + b1;
    }
}

// ---------------- launch ----------------

extern "C" void kernel_launch(void* const* d_in, const int* in_sizes, int n_in,
                              void* d_out, int out_size, void* d_ws, size_t ws_size,
                              hipStream_t stream) {
    const float* x      = (const float*)d_in[0];
    const int*   e1_row = (const int*)d_in[1];
    const int*   e1_col = (const int*)d_in[2];
    const float* e1_val = (const float*)d_in[3];
    const int*   e2_row = (const int*)d_in[4];
    const int*   e2_col = (const int*)d_in[5];
    const float* e2_val = (const float*)d_in[6];
    const float* W_emb  = (const float*)d_in[7];
    const float* b_emb  = (const float*)d_in[8];
    const float* bn0_g  = (const float*)d_in[9];
    const float* bn0_b  = (const float*)d_in[10];
    const float* bn1_g  = (const float*)d_in[11];
    const float* bn1_b  = (const float*)d_in[12];
    const float* W_head = (const float*)d_in[13];
    const float* b_head = (const float*)d_in[14];
    float* out = (float*)d_out;

    char* ws = (char*)d_ws;
    auto alloc = [&](size_t bytes) -> char* {
        char* p = ws;
        ws += (bytes + 255) & ~(size_t)255;
        return p;
    };
    int*   rp1   = (int*)alloc((NN + 1) * 4);
    int*   rp2   = (int*)alloc((NN + 1) * 4);
    int*   bc1   = (int*)alloc((size_t)G1B * NBKT * 4);
    int*   bc2   = (int*)alloc((size_t)G2B * NBKT * 4);
    unsigned int* Ed1 = (unsigned int*)alloc((size_t)E1N * 4);
    unsigned int* Ed2 = (unsigned int*)alloc((size_t)E2N * 4);
    float* stats = (float*)alloc(1536 * 4);
    unsigned short* Wbh  = (unsigned short*)alloc(3840 * 8 * 2);
    unsigned short* Wbe  = (unsigned short*)alloc(2048 * 8 * 2);
    unsigned char*  C1f8 = (unsigned char*)alloc((size_t)NN * 256);
    unsigned short* Jh   = (unsigned short*)alloc((size_t)NN * LD * 2);
    // temp 8B records alias Jh (dead until embed writes it): T1 then T2
    uint2* T1 = (uint2*)Jh;
    uint2* T2 = T1 + E1N;

    float* sum0   = stats;        float* sq0    = stats + 128;
    float* sum1   = stats + 256;  float* sq1    = stats + 512;
    float* scale0 = stats + 768;  float* shift0 = stats + 896;
    float* scale1 = stats + 1024; float* shift1 = stats + 1280;

    // CSR build (LDS counting sort) + weight packs
    zero_kernel<<<3, 256, 0, stream>>>(stats, 768);
    bucket_count_kernel<<<G1B + G2B, 256, 0, stream>>>(e1_row, e2_row, bc1, bc2);
    bucket_scan_kernel<<<1, 512, 0, stream>>>(bc1, bc2);
    bucket_place_kernel<<<G1B + G2B, 256, 0, stream>>>(e1_row, e1_col, e1_val,
                                                       e2_row, e2_col, e2_val, bc1, bc2, T1, T2);
    bucket_sort_kernel<<<2 * NBKT, 256, 0, stream>>>(bc1, T1, rp1, Ed1, bc2, T2, rp2, Ed2);
    packw_kernel<<<15, 256, 0, stream>>>(W_head, Wbh, 32, 30, 3840);
    packw_kernel<<<8, 256, 0, stream>>>(W_emb, Wbe, 64, 8, 2048);

    // embed -> Jh[:,0:64) (MFMA)  (T1/T2 are dead from here on)
    embed_mfma_kernel<<<(NT + 3) / 4, 256, 0, stream>>>(x, Wbe, b_emb, Jh);

    // conv0 -> Jh[:,64:192), then BN
    spmm_bf16_kernel<16><<<2 * (NN / 16), 256, 0, stream>>>(rp1, Ed1, rp2, Ed2, Jh, Jh + 64);
    bn_stats_kernel<128><<<512, 256, 0, stream>>>(Jh + 64, sum0, sq0);
    bn_finalize_kernel<<<1, 128, 0, stream>>>(sum0, sq0, bn0_g, bn0_b, scale0, shift0, 128);
    bn_apply_kernel<128><<<(NN * 32 + 255) / 256, 256, 0, stream>>>(Jh + 64, scale0, shift0);

    // conv1 -> Jh[:,192:448), then BN + fp8 copy
    spmm_bf16_kernel<32><<<2 * (NN / 8), 256, 0, stream>>>(rp1, Ed1, rp2, Ed2, Jh + 64, Jh + 192);
    bn_stats_kernel<256><<<512, 256, 0, stream>>>(Jh + 192, sum1, sq1);
    bn_finalize_kernel<<<1, 256, 0, stream>>>(sum1, sq1, bn1_g, bn1_b, scale1, shift1, 256);
    bn_apply_fp8_kernel<<<(NN * 64 + 255) / 256, 256, 0, stream>>>(Jh + 192, C1f8, scale1, shift1);

    // conv2 -> Jh[:,448:960) (fp8 src)
    spmm_fp8_kernel<<<2 * (NN / 4), 256, 0, stream>>>(rp1, Ed1, rp2, Ed2, C1f8, Jh + 448);

    // head (MFMA)
    head_mfma_kernel<<<(NT + 3) / 4, 256, 0, stream>>>(Jh, Wbh, b_head, out);
}

// Round 12
// 541.966 us; speedup vs baseline: 2.7670x; 1.0225x over previous
//
#include <hip/hip_runtime.h>

// H2GCN forward, bf16 activations in fused Jh[N,960]:
//   cols [0,64)=h [64,192)=c0 [192,448)=c1 [448,960)=c2.
// CSR build = two-level LDS counting sort (r10).
// conv0: bf16 gather 4 feats/lane. conv1: bf16 gather 8 feats/lane (16B loads).
// conv2: fp8 e4m3 gather 8 feats/lane (fp8 ONLY at the leaf conv — r11 showed
//   fp8 on conv0/conv1 cascades through BN chain: absmax 0.125 > 0.0747 FAIL).
// Embed + Head: MFMA 16x16x32 bf16, weights pre-packed to B-fragment layout.

#define NN  50000
#define E1N 800000
#define E2N 1600000
#define LD  960
#define NT  3125         // 16-node tiles
#define NBKT 391         // 128-row buckets
#define CHUNK 8192
#define G1B 98           // ceil(E1N/CHUNK)
#define G2B 196          // ceil(E2N/CHUNK)

typedef short bf16x8 __attribute__((ext_vector_type(8)));
typedef float f32x4  __attribute__((ext_vector_type(4)));
typedef float f32x2  __attribute__((ext_vector_type(2)));

__device__ __forceinline__ float bfl(unsigned int w) { return __uint_as_float(w << 16); }
__device__ __forceinline__ float bfh(unsigned int w) { return __uint_as_float(w & 0xFFFF0000u); }
__device__ __forceinline__ float bf2f(unsigned short u) { return __uint_as_float(((unsigned int)u) << 16); }
__device__ __forceinline__ unsigned short f2bf(float f) {         // RNE
    unsigned int u = __float_as_uint(f);
    u += 0x7FFFu + ((u >> 16) & 1u);
    return (unsigned short)(u >> 16);
}
__device__ __forceinline__ unsigned int pack2(float a, float b) {
    return (unsigned int)f2bf(a) | ((unsigned int)f2bf(b) << 16);
}
__device__ __forceinline__ unsigned int packfp8(float a, float b, float c, float d) {
    int w = __builtin_amdgcn_cvt_pk_fp8_f32(a, b, 0, false);
    w     = __builtin_amdgcn_cvt_pk_fp8_f32(c, d, w, true);
    return (unsigned int)w;
}

// ---------------- CSR build ----------------

__global__ __launch_bounds__(256) void zero_kernel(float* c, int nc) {
    int i = blockIdx.x * 256 + threadIdx.x;
    if (i < nc) c[i] = 0.f;
}

__global__ __launch_bounds__(256) void bucket_count_kernel(const int* __restrict__ r1,
                                                           const int* __restrict__ r2,
                                                           int* __restrict__ bc1, int* __restrict__ bc2) {
    __shared__ int cnt[NBKT];
    for (int t = threadIdx.x; t < NBKT; t += 256) cnt[t] = 0;
    __syncthreads();
    int blk = blockIdx.x;
    const int* r; int base, lim; int* bc;
    if (blk < G1B) { r = r1; base = blk * CHUNK; lim = min(base + CHUNK, E1N); bc = bc1 + blk * NBKT; }
    else { int b2 = blk - G1B; r = r2; base = b2 * CHUNK; lim = min(base + CHUNK, E2N); bc = bc2 + b2 * NBKT; }
    for (int i = base + threadIdx.x; i < lim; i += 256)
        atomicAdd(&cnt[r[i] >> 7], 1);
    __syncthreads();
    for (int t = threadIdx.x; t < NBKT; t += 256) bc[t] = cnt[t];
}

__global__ __launch_bounds__(512) void bucket_scan_kernel(int* __restrict__ bc1, int* __restrict__ bc2) {
    __shared__ int s[512];
    int t = threadIdx.x;
    int tot1 = 0, tot2 = 0;
    if (t < NBKT) {
        for (int b = 0; b < G1B; b++) tot1 += bc1[b * NBKT + t];
        for (int b = 0; b < G2B; b++) tot2 += bc2[b * NBKT + t];
    }
    s[t] = (t < NBKT) ? tot1 : 0;
    __syncthreads();
    for (int off = 1; off < 512; off <<= 1) {
        int v = (t >= off) ? s[t - off] : 0;
        __syncthreads(); s[t] += v; __syncthreads();
    }
    int base1 = ((t < NBKT) ? s[t] : 0) - tot1;
    __syncthreads();
    s[t] = (t < NBKT) ? tot2 : 0;
    __syncthreads();
    for (int off = 1; off < 512; off <<= 1) {
        int v = (t >= off) ? s[t - off] : 0;
        __syncthreads(); s[t] += v; __syncthreads();
    }
    int base2 = ((t < NBKT) ? s[t] : 0) - tot2;
    if (t < NBKT) {
        int run = base1;
        for (int b = 0; b < G1B; b++) { int v = bc1[b * NBKT + t]; bc1[b * NBKT + t] = run; run += v; }
        run = base2;
        for (int b = 0; b < G2B; b++) { int v = bc2[b * NBKT + t]; bc2[b * NBKT + t] = run; run += v; }
    }
}

__global__ __launch_bounds__(256) void bucket_place_kernel(
        const int* __restrict__ r1, const int* __restrict__ c1, const float* __restrict__ v1,
        const int* __restrict__ r2, const int* __restrict__ c2, const float* __restrict__ v2,
        const int* __restrict__ bc1, const int* __restrict__ bc2,
        uint2* __restrict__ T1, uint2* __restrict__ T2) {
    __shared__ int pos[NBKT];
    int blk = blockIdx.x;
    const int *r, *c; const float* v; int base, lim; const int* bc; uint2* T;
    if (blk < G1B) { r = r1; c = c1; v = v1; base = blk * CHUNK; lim = min(base + CHUNK, E1N);
                     bc = bc1 + blk * NBKT; T = T1; }
    else { int b2 = blk - G1B; r = r2; c = c2; v = v2; base = b2 * CHUNK; lim = min(base + CHUNK, E2N);
           bc = bc2 + b2 * NBKT; T = T2; }
    for (int t = threadIdx.x; t < NBKT; t += 256) pos[t] = bc[t];
    __syncthreads();
    for (int i = base + threadIdx.x; i < lim; i += 256) {
        int row = r[i];
        int p = atomicAdd(&pos[row >> 7], 1);
        T[p] = make_uint2(((unsigned)c[i] << 16) | (unsigned)row, __float_as_uint(v[i]));
    }
}

__global__ __launch_bounds__(256) void bucket_sort_kernel(
        const int* __restrict__ bb1, const uint2* __restrict__ T1, int* __restrict__ rp1, unsigned int* __restrict__ Ed1,
        const int* __restrict__ bb2, const uint2* __restrict__ T2, int* __restrict__ rp2, unsigned int* __restrict__ Ed2) {
    int b = blockIdx.x % NBKT;
    int g = blockIdx.x / NBKT;
    const int* bb = g ? bb2 : bb1;
    const uint2* T = g ? T2 : T1;
    int* rp = g ? rp2 : rp1;
    unsigned int* Ed = g ? Ed2 : Ed1;
    int EN = g ? E2N : E1N;
    int beg = bb[b];
    int end = (b == NBKT - 1) ? EN : bb[b + 1];
    int R0 = b * 128;
    int nrows = min(128, NN - R0);
    __shared__ int cnt[129];
    __shared__ int cur[128];
    for (int t = threadIdx.x; t < 129; t += 256) cnt[t] = 0;
    __syncthreads();
    for (int i = beg + threadIdx.x; i < end; i += 256)
        atomicAdd(&cnt[((T[i].x & 0xFFFFu) & 127) + 1], 1);
    __syncthreads();
    for (int off = 1; off < 129; off <<= 1) {
        int v = 0;
        if (threadIdx.x < 129 && (int)threadIdx.x >= off) v = cnt[threadIdx.x - off];
        __syncthreads();
        if (threadIdx.x < 129) cnt[threadIdx.x] += v;
        __syncthreads();
    }
    if ((int)threadIdx.x < nrows) {
        int p = beg + cnt[threadIdx.x];
        cur[threadIdx.x] = p;
        rp[R0 + threadIdx.x] = p;
    }
    if (b == NBKT - 1 && threadIdx.x == 0) rp[NN] = end;
    __syncthreads();
    for (int i = beg + threadIdx.x; i < end; i += 256) {
        uint2 rec = T[i];
        int rl = (rec.x & 0xFFFFu) & 127;
        int p = atomicAdd(&cur[rl], 1);
        Ed[p] = (rec.x & 0xFFFF0000u) | (unsigned)f2bf(__uint_as_float(rec.y));
    }
}

// ---------------- weight -> bf16 B-fragment pack ----------------
__global__ __launch_bounds__(256) void packw_kernel(const float* __restrict__ W, unsigned short* __restrict__ Wb,
                                                    int NC, int kbs, int total) {
    int i = blockIdx.x * 256 + threadIdx.x;
    if (i >= total) return;
    int lane  = i & 63;
    int kb    = (i >> 6) % kbs;
    int ctile = i / (kbs * 64);
    int n  = ctile * 16 + (lane & 15);
    int k0 = kb * 32 + (lane >> 4) * 8;
    unsigned short v[8];
    #pragma unroll
    for (int j = 0; j < 8; j++) v[j] = f2bf(W[(k0 + j) * NC + n]);
    *(uint4*)(Wb + (size_t)i * 8) = *(uint4*)v;
}

// ---------------- embed via MFMA ----------------
__global__ __launch_bounds__(256) void embed_mfma_kernel(const float* __restrict__ x,
                                                         const unsigned short* __restrict__ Wb,
                                                         const float* __restrict__ bias,
                                                         unsigned short* __restrict__ Jh) {
    int wave = threadIdx.x >> 6;
    int lane = threadIdx.x & 63;
    int tile = blockIdx.x * 4 + wave;
    if (tile >= NT) return;
    int m = lane & 15;
    int q = lane >> 4;
    const float* xr = x + (size_t)(tile * 16 + m) * 256 + q * 8;
    const unsigned short* bbase = Wb + (size_t)lane * 8;
    f32x4 acc[4];
    #pragma unroll
    for (int ct = 0; ct < 4; ct++) acc[ct] = (f32x4){0.f, 0.f, 0.f, 0.f};
    #pragma unroll
    for (int kb = 0; kb < 8; kb++) {
        float4 xa = *(const float4*)(xr + kb * 32);
        float4 xb = *(const float4*)(xr + kb * 32 + 4);
        unsigned short av[8];
        av[0] = f2bf(xa.x); av[1] = f2bf(xa.y); av[2] = f2bf(xa.z); av[3] = f2bf(xa.w);
        av[4] = f2bf(xb.x); av[5] = f2bf(xb.y); av[6] = f2bf(xb.z); av[7] = f2bf(xb.w);
        bf16x8 a = *(bf16x8*)av;
        #pragma unroll
        for (int ct = 0; ct < 4; ct++) {
            bf16x8 bfr = *(const bf16x8*)(bbase + (size_t)(ct * 8 + kb) * 512);
            acc[ct] = __builtin_amdgcn_mfma_f32_16x16x32_bf16(a, bfr, acc[ct], 0, 0, 0);
        }
    }
    #pragma unroll
    for (int ct = 0; ct < 4; ct++) {
        int col = ct * 16 + m;
        float bb = bias[col];
        #pragma unroll
        for (int r = 0; r < 4; r++) {
            float v = fmaxf(acc[ct][r] + bb, 0.f);
            Jh[(size_t)(tile * 16 + q * 4 + r) * LD + col] = f2bf(v);
        }
    }
}

// ---------------- pull SPMM, bf16 source, 4 feats/lane (conv0) ----------------
template <int LPR>
__global__ __launch_bounds__(256) void spmm_bf16_kernel(
        const int* __restrict__ rp1, const unsigned int* __restrict__ ed1,
        const int* __restrict__ rp2, const unsigned int* __restrict__ ed2,
        const unsigned short* __restrict__ src, unsigned short* __restrict__ dst) {
    constexpr int ROWS = 64 / LPR;
    constexpr int SRCF = LPR * 4;
    constexpr int GB   = NN / (ROWS * 4);
    int g    = (blockIdx.x >= GB) ? 1 : 0;
    int bx   = blockIdx.x - g * GB;
    int wave = threadIdx.x >> 6;
    int lane = threadIdx.x & 63;
    int grp  = lane / LPR;
    int sub  = lane % LPR;
    int row  = (bx * 4 + wave) * ROWS + grp;
    const int*          rp = g ? rp2 : rp1;
    const unsigned int* ed = g ? ed2 : ed1;
    int beg = rp[row], end = rp[row + 1];

    float acc[4] = {0.f, 0.f, 0.f, 0.f};
    const unsigned short* sbase = src + sub * 4;

    int j = beg;
    for (; j + 8 <= end; j += 8) {
        unsigned int e[8];
        #pragma unroll
        for (int u = 0; u < 8; u++) e[u] = ed[j + u];
        uint2 s[8];
        #pragma unroll
        for (int u = 0; u < 8; u++) s[u] = *(const uint2*)(sbase + (size_t)(e[u] >> 16) * LD);
        #pragma unroll
        for (int u = 0; u < 8; u++) {
            float v = bfl(e[u]);
            acc[0]=fmaf(v,bfl(s[u].x),acc[0]); acc[1]=fmaf(v,bfh(s[u].x),acc[1]);
            acc[2]=fmaf(v,bfl(s[u].y),acc[2]); acc[3]=fmaf(v,bfh(s[u].y),acc[3]);
        }
    }
    for (; j < end; j++) {
        unsigned int e = ed[j];
        float v = bfl(e);
        uint2 s = *(const uint2*)(sbase + (size_t)(e >> 16) * LD);
        acc[0]=fmaf(v,bfl(s.x),acc[0]); acc[1]=fmaf(v,bfh(s.x),acc[1]);
        acc[2]=fmaf(v,bfl(s.y),acc[2]); acc[3]=fmaf(v,bfh(s.y),acc[3]);
    }

    unsigned short* dp = dst + (size_t)row * LD + g * SRCF + sub * 4;
    uint2 o; o.x = pack2(acc[0], acc[1]); o.y = pack2(acc[2], acc[3]);
    *(uint2*)dp = o;
}

// ---------------- pull SPMM, bf16 source, 8 feats/lane, 16B loads (conv1) ----------------
template <int LPR>
__global__ __launch_bounds__(256) void spmm_bf16x8_kernel(
        const int* __restrict__ rp1, const unsigned int* __restrict__ ed1,
        const int* __restrict__ rp2, const unsigned int* __restrict__ ed2,
        const unsigned short* __restrict__ src, unsigned short* __restrict__ dst) {
    constexpr int ROWS = 64 / LPR;
    constexpr int SRCF = LPR * 8;
    constexpr int GB   = NN / (ROWS * 4);
    int g    = (blockIdx.x >= GB) ? 1 : 0;
    int bx   = blockIdx.x - g * GB;
    int wave = threadIdx.x >> 6;
    int lane = threadIdx.x & 63;
    int grp  = lane / LPR;
    int sub  = lane % LPR;
    int row  = (bx * 4 + wave) * ROWS + grp;
    const int*          rp = g ? rp2 : rp1;
    const unsigned int* ed = g ? ed2 : ed1;
    int beg = rp[row], end = rp[row + 1];

    float acc[8];
    #pragma unroll
    for (int u = 0; u < 8; u++) acc[u] = 0.f;
    const unsigned short* sbase = src + sub * 8;

    int j = beg;
    for (; j + 4 <= end; j += 4) {
        unsigned int e[4];
        #pragma unroll
        for (int u = 0; u < 4; u++) e[u] = ed[j + u];
        uint4 s[4];
        #pragma unroll
        for (int u = 0; u < 4; u++) s[u] = *(const uint4*)(sbase + (size_t)(e[u] >> 16) * LD);
        #pragma unroll
        for (int u = 0; u < 4; u++) {
            float v = bfl(e[u]);
            acc[0]=fmaf(v,bfl(s[u].x),acc[0]); acc[1]=fmaf(v,bfh(s[u].x),acc[1]);
            acc[2]=fmaf(v,bfl(s[u].y),acc[2]); acc[3]=fmaf(v,bfh(s[u].y),acc[3]);
            acc[4]=fmaf(v,bfl(s[u].z),acc[4]); acc[5]=fmaf(v,bfh(s[u].z),acc[5]);
            acc[6]=fmaf(v,bfl(s[u].w),acc[6]); acc[7]=fmaf(v,bfh(s[u].w),acc[7]);
        }
    }
    for (; j < end; j++) {
        unsigned int e = ed[j];
        float v = bfl(e);
        uint4 s = *(const uint4*)(sbase + (size_t)(e >> 16) * LD);
        acc[0]=fmaf(v,bfl(s.x),acc[0]); acc[1]=fmaf(v,bfh(s.x),acc[1]);
        acc[2]=fmaf(v,bfl(s.y),acc[2]); acc[3]=fmaf(v,bfh(s.y),acc[3]);
        acc[4]=fmaf(v,bfl(s.z),acc[4]); acc[5]=fmaf(v,bfh(s.z),acc[5]);
        acc[6]=fmaf(v,bfl(s.w),acc[6]); acc[7]=fmaf(v,bfh(s.w),acc[7]);
    }

    unsigned short* dp = dst + (size_t)row * LD + g * SRCF + sub * 8;
    uint4 o;
    o.x = pack2(acc[0], acc[1]); o.y = pack2(acc[2], acc[3]);
    o.z = pack2(acc[4], acc[5]); o.w = pack2(acc[6], acc[7]);
    *(uint4*)dp = o;
}

// ---------------- pull SPMM, fp8 source, 8 feats/lane (conv2) ----------------
template <int LPR>
__global__ __launch_bounds__(256) void spmm_fp8x8_kernel(
        const int* __restrict__ rp1, const unsigned int* __restrict__ ed1,
        const int* __restrict__ rp2, const unsigned int* __restrict__ ed2,
        const unsigned char* __restrict__ src8,   // [N, LPR*8] fp8
        unsigned short* __restrict__ dst) {
    constexpr int ROWS = 64 / LPR;
    constexpr int SRCF = LPR * 8;
    constexpr int GB   = NN / (ROWS * 4);
    int g    = (blockIdx.x >= GB) ? 1 : 0;
    int bx   = blockIdx.x - g * GB;
    int wave = threadIdx.x >> 6;
    int lane = threadIdx.x & 63;
    int grp  = lane / LPR;
    int sub  = lane % LPR;
    int row  = (bx * 4 + wave) * ROWS + grp;
    const int*          rp = g ? rp2 : rp1;
    const unsigned int* ed = g ? ed2 : ed1;
    int beg = rp[row], end = rp[row + 1];

    float acc[8];
    #pragma unroll
    for (int u = 0; u < 8; u++) acc[u] = 0.f;
    const unsigned char* sbase = src8 + sub * 8;

    int j = beg;
    for (; j + 8 <= end; j += 8) {
        unsigned int e[8];
        #pragma unroll
        for (int u = 0; u < 8; u++) e[u] = ed[j + u];
        uint2 s[8];
        #pragma unroll
        for (int u = 0; u < 8; u++) s[u] = *(const uint2*)(sbase + (size_t)(e[u] >> 16) * SRCF);
        #pragma unroll
        for (int u = 0; u < 8; u++) {
            float v = bfl(e[u]);
            f32x2 a0 = __builtin_amdgcn_cvt_pk_f32_fp8(s[u].x, false);
            f32x2 a1 = __builtin_amdgcn_cvt_pk_f32_fp8(s[u].x, true);
            f32x2 a2 = __builtin_amdgcn_cvt_pk_f32_fp8(s[u].y, false);
            f32x2 a3 = __builtin_amdgcn_cvt_pk_f32_fp8(s[u].y, true);
            acc[0]=fmaf(v,a0[0],acc[0]); acc[1]=fmaf(v,a0[1],acc[1]);
            acc[2]=fmaf(v,a1[0],acc[2]); acc[3]=fmaf(v,a1[1],acc[3]);
            acc[4]=fmaf(v,a2[0],acc[4]); acc[5]=fmaf(v,a2[1],acc[5]);
            acc[6]=fmaf(v,a3[0],acc[6]); acc[7]=fmaf(v,a3[1],acc[7]);
        }
    }
    for (; j < end; j++) {
        unsigned int e = ed[j];
        float v = bfl(e);
        uint2 s = *(const uint2*)(sbase + (size_t)(e >> 16) * SRCF);
        f32x2 a0 = __builtin_amdgcn_cvt_pk_f32_fp8(s.x, false);
        f32x2 a1 = __builtin_amdgcn_cvt_pk_f32_fp8(s.x, true);
        f32x2 a2 = __builtin_amdgcn_cvt_pk_f32_fp8(s.y, false);
        f32x2 a3 = __builtin_amdgcn_cvt_pk_f32_fp8(s.y, true);
        acc[0]=fmaf(v,a0[0],acc[0]); acc[1]=fmaf(v,a0[1],acc[1]);
        acc[2]=fmaf(v,a1[0],acc[2]); acc[3]=fmaf(v,a1[1],acc[3]);
        acc[4]=fmaf(v,a2[0],acc[4]); acc[5]=fmaf(v,a2[1],acc[5]);
        acc[6]=fmaf(v,a3[0],acc[6]); acc[7]=fmaf(v,a3[1],acc[7]);
    }

    unsigned short* dp = dst + (size_t)row * LD + g * SRCF + sub * 8;
    uint4 o;
    o.x = pack2(acc[0], acc[1]); o.y = pack2(acc[2], acc[3]);
    o.z = pack2(acc[4], acc[5]); o.w = pack2(acc[6], acc[7]);
    *(uint4*)dp = o;
}

// ---------------- BN stats / finalize / apply ----------------
template <int F>
__global__ __launch_bounds__(256) void bn_stats_kernel(const unsigned short* __restrict__ c,
                                                       float* sum, float* sumsq) {
    constexpr int SL = 256 / F;
    int f  = threadIdx.x % F;
    int sl = threadIdx.x / F;
    float s = 0.f, ss = 0.f;
    for (int r = blockIdx.x * SL + sl; r < NN; r += gridDim.x * SL) {
        float v = bf2f(c[(size_t)r * LD + f]);
        s += v; ss += v * v;
    }
    __shared__ float ls[256], lss[256];
    ls[threadIdx.x] = s; lss[threadIdx.x] = ss;
    __syncthreads();
    if (sl == 0) {
        #pragma unroll
        for (int u = 1; u < SL; u++) { s += ls[f + u * F]; ss += lss[f + u * F]; }
        atomicAdd(&sum[f], s);
        atomicAdd(&sumsq[f], ss);
    }
}

__global__ void bn_finalize_kernel(const float* sum, const float* sumsq, const float* __restrict__ gamma,
                                   const float* __restrict__ beta, float* scale, float* shift, int F) {
    int f = blockIdx.x * blockDim.x + threadIdx.x;
    if (f >= F) return;
    float m   = sum[f] * (1.0f / NN);
    float var = sumsq[f] * (1.0f / NN) - m * m;
    float sc  = gamma[f] * rsqrtf(var + 1e-5f);
    scale[f] = sc;
    shift[f] = beta[f] - m * sc;
}

template <int F>
__global__ __launch_bounds__(256) void bn_apply_kernel(unsigned short* __restrict__ c,
                                                       const float* __restrict__ scale,
                                                       const float* __restrict__ shift) {
    constexpr int FV = F / 4;
    int idx  = blockIdx.x * 256 + threadIdx.x;
    int node = idx / FV;
    int fo   = (idx % FV) * 4;
    if (node >= NN) return;
    unsigned short* p = c + (size_t)node * LD + fo;
    uint2 v = *(uint2*)p;
    float a0 = bfl(v.x), a1 = bfh(v.x), a2 = bfl(v.y), a3 = bfh(v.y);
    float4 sc = *(const float4*)(scale + fo);
    float4 sh = *(const float4*)(shift + fo);
    a0 = fmaf(a0, sc.x, sh.x);
    a1 = fmaf(a1, sc.y, sh.y);
    a2 = fmaf(a2, sc.z, sh.z);
    a3 = fmaf(a3, sc.w, sh.w);
    v.x = pack2(a0, a1); v.y = pack2(a2, a3);
    *(uint2*)p = v;
}

// BN apply on c1 (F=256): bf16 in-place AND fp8 copy for conv2's gather
__global__ __launch_bounds__(256) void bn_apply_fp8_kernel(unsigned short* __restrict__ c,
                                                           unsigned char* __restrict__ c8,
                                                           const float* __restrict__ scale,
                                                           const float* __restrict__ shift) {
    int idx  = blockIdx.x * 256 + threadIdx.x;
    int node = idx >> 6;
    int fo   = (idx & 63) * 4;
    if (node >= NN) return;
    unsigned short* p = c + (size_t)node * LD + fo;
    uint2 v = *(uint2*)p;
    float a0 = bfl(v.x), a1 = bfh(v.x), a2 = bfl(v.y), a3 = bfh(v.y);
    float4 sc = *(const float4*)(scale + fo);
    float4 sh = *(const float4*)(shift + fo);
    a0 = fmaf(a0, sc.x, sh.x);
    a1 = fmaf(a1, sc.y, sh.y);
    a2 = fmaf(a2, sc.z, sh.z);
    a3 = fmaf(a3, sc.w, sh.w);
    v.x = pack2(a0, a1); v.y = pack2(a2, a3);
    *(uint2*)p = v;
    *(unsigned int*)(c8 + (size_t)node * 256 + fo) = packfp8(a0, a1, a2, a3);
}

// ---------------- head GEMM via MFMA ----------------
__global__ __launch_bounds__(256) void head_mfma_kernel(const unsigned short* __restrict__ Jh,
                                                        const unsigned short* __restrict__ Wb,
                                                        const float* __restrict__ b,
                                                        float* __restrict__ out) {
    int wave = threadIdx.x >> 6;
    int lane = threadIdx.x & 63;
    int tile = blockIdx.x * 4 + wave;
    if (tile >= NT) return;
    int m = lane & 15;
    int q = lane >> 4;
    const unsigned short* arow  = Jh + (size_t)(tile * 16 + m) * LD + q * 8;
    const unsigned short* bbase = Wb + (size_t)lane * 8;
    f32x4 acc0 = {0.f, 0.f, 0.f, 0.f};
    f32x4 acc1 = {0.f, 0.f, 0.f, 0.f};
    #pragma unroll 5
    for (int kb = 0; kb < 30; kb++) {
        bf16x8 a  = *(const bf16x8*)(arow + kb * 32);
        bf16x8 b0 = *(const bf16x8*)(bbase + (size_t)kb * 512);
        bf16x8 b1 = *(const bf16x8*)(bbase + (size_t)(30 + kb) * 512);
        acc0 = __builtin_amdgcn_mfma_f32_16x16x32_bf16(a, b0, acc0, 0, 0, 0);
        acc1 = __builtin_amdgcn_mfma_f32_16x16x32_bf16(a, b1, acc1, 0, 0, 0);
    }
    int col = m;
    float b0 = b[col], b1 = b[16 + col];
    #pragma unroll
    for (int r = 0; r < 4; r++) {
        float* op = out + (size_t)(tile * 16 + q * 4 + r) * 32 + col;
        op[0]  = acc0[r] + b0;
        op[16] = acc1[r] + b1;
    }
}

// ---------------- launch ----------------

extern "C" void kernel_launch(void* const* d_in, const int* in_sizes, int n_in,
                              void* d_out, int out_size, void* d_ws, size_t ws_size,
                              hipStream_t stream) {
    const float* x      = (const float*)d_in[0];
    const int*   e1_row = (const int*)d_in[1];
    const int*   e1_col = (const int*)d_in[2];
    const float* e1_val = (const float*)d_in[3];
    const int*   e2_row = (const int*)d_in[4];
    const int*   e2_col = (const int*)d_in[5];
    const float* e2_val = (const float*)d_in[6];
    const float* W_emb  = (const float*)d_in[7];
    const float* b_emb  = (const float*)d_in[8];
    const float* bn0_g  = (const float*)d_in[9];
    const float* bn0_b  = (const float*)d_in[10];
    const float* bn1_g  = (const float*)d_in[11];
    const float* bn1_b  = (const float*)d_in[12];
    const float* W_head = (const float*)d_in[13];
    const float* b_head = (const float*)d_in[14];
    float* out = (float*)d_out;

    char* ws = (char*)d_ws;
    auto alloc = [&](size_t bytes) -> char* {
        char* p = ws;
        ws += (bytes + 255) & ~(size_t)255;
        return p;
    };
    int*   rp1   = (int*)alloc((NN + 1) * 4);
    int*   rp2   = (int*)alloc((NN + 1) * 4);
    int*   bc1   = (int*)alloc((size_t)G1B * NBKT * 4);
    int*   bc2   = (int*)alloc((size_t)G2B * NBKT * 4);
    unsigned int* Ed1 = (unsigned int*)alloc((size_t)E1N * 4);
    unsigned int* Ed2 = (unsigned int*)alloc((size_t)E2N * 4);
    float* stats = (float*)alloc(1536 * 4);
    unsigned short* Wbh  = (unsigned short*)alloc(3840 * 8 * 2);
    unsigned short* Wbe  = (unsigned short*)alloc(2048 * 8 * 2);
    unsigned char*  C1f8 = (unsigned char*)alloc((size_t)NN * 256);
    unsigned short* Jh   = (unsigned short*)alloc((size_t)NN * LD * 2);
    // temp 8B records alias Jh (dead until embed writes it)
    uint2* T1 = (uint2*)Jh;
    uint2* T2 = T1 + E1N;

    float* sum0   = stats;        float* sq0    = stats + 128;
    float* sum1   = stats + 256;  float* sq1    = stats + 512;
    float* scale0 = stats + 768;  float* shift0 = stats + 896;
    float* scale1 = stats + 1024; float* shift1 = stats + 1280;

    // CSR build (LDS counting sort) + weight packs
    zero_kernel<<<3, 256, 0, stream>>>(stats, 768);
    bucket_count_kernel<<<G1B + G2B, 256, 0, stream>>>(e1_row, e2_row, bc1, bc2);
    bucket_scan_kernel<<<1, 512, 0, stream>>>(bc1, bc2);
    bucket_place_kernel<<<G1B + G2B, 256, 0, stream>>>(e1_row, e1_col, e1_val,
                                                       e2_row, e2_col, e2_val, bc1, bc2, T1, T2);
    bucket_sort_kernel<<<2 * NBKT, 256, 0, stream>>>(bc1, T1, rp1, Ed1, bc2, T2, rp2, Ed2);
    packw_kernel<<<15, 256, 0, stream>>>(W_head, Wbh, 32, 30, 3840);
    packw_kernel<<<8, 256, 0, stream>>>(W_emb, Wbe, 64, 8, 2048);

    // embed -> Jh[:,0:64) (MFMA)  (T1/T2 dead from here on)
    embed_mfma_kernel<<<(NT + 3) / 4, 256, 0, stream>>>(x, Wbe, b_emb, Jh);

    // conv0 (bf16 h) -> Jh[:,64:192), then BN
    spmm_bf16_kernel<16><<<2 * (NN / 16), 256, 0, stream>>>(rp1, Ed1, rp2, Ed2, Jh, Jh + 64);
    bn_stats_kernel<128><<<512, 256, 0, stream>>>(Jh + 64, sum0, sq0);
    bn_finalize_kernel<<<1, 128, 0, stream>>>(sum0, sq0, bn0_g, bn0_b, scale0, shift0, 128);
    bn_apply_kernel<128><<<(NN * 32 + 255) / 256, 256, 0, stream>>>(Jh + 64, scale0, shift0);

    // conv1 (bf16 c0', 16B loads) -> Jh[:,192:448), then BN + fp8 copy
    spmm_bf16x8_kernel<16><<<2 * (NN / 16), 256, 0, stream>>>(rp1, Ed1, rp2, Ed2, Jh + 64, Jh + 192);
    bn_stats_kernel<256><<<512, 256, 0, stream>>>(Jh + 192, sum1, sq1);
    bn_finalize_kernel<<<1, 256, 0, stream>>>(sum1, sq1, bn1_g, bn1_b, scale1, shift1, 256);
    bn_apply_fp8_kernel<<<(NN * 64 + 255) / 256, 256, 0, stream>>>(Jh + 192, C1f8, scale1, shift1);

    // conv2 (fp8 c1', 8 feats/lane) -> Jh[:,448:960)
    spmm_fp8x8_kernel<32><<<2 * (NN / 8), 256, 0, stream>>>(rp1, Ed1, rp2, Ed2, C1f8, Jh + 448);

    // head (MFMA)
    head_mfma_kernel<<<(NT + 3) / 4, 256, 0, stream>>>(Jh, Wbh, b_head, out);
}